// Round 1
// baseline (792.531 us; speedup 1.0000x reference)
//
#include <hip/hip_runtime.h>
#include <stdint.h>
#include <math.h>

typedef unsigned short u16;
typedef __attribute__((ext_vector_type(8))) short short8;
typedef __attribute__((ext_vector_type(4))) float f32x4;

#define A0C 0.44721359549995793f
#define A1C 0.77459666924148340f
#define INV3C 0.57735026918962584f
#define INV6C 0.40824829046386302f

__device__ __forceinline__ float bf2f(u16 u) {
    unsigned v = ((unsigned)u) << 16; float f; __builtin_memcpy(&f, &v, 4); return f;
}
__device__ __forceinline__ u16 f2bf(float f) {
    unsigned u; __builtin_memcpy(&u, &f, 4);
    u += 0x7fffu + ((u >> 16) & 1u);
    return (u16)(u >> 16);
}

__device__ __forceinline__ void gload_lds16(const void* g, void* l) {
    __builtin_amdgcn_global_load_lds((const __attribute__((address_space(1))) unsigned*)g,
                                     (__attribute__((address_space(3))) unsigned*)l, 16, 0, 0);
}

// ---------------- weight transpose + bf16 convert ----------------
struct WDesc { const float* s; u16* d; int n; float sc; };
struct WArgs { WDesc w[12]; };

__global__ void cvt_weights(WArgs args) {
    WDesc wd = args.w[blockIdx.z];
    int n = wd.n;
    int x0 = blockIdx.x * 32, y0 = blockIdx.y * 32;
    if (x0 >= n || y0 >= n) return;
    __shared__ float tile[32][33];
    int tx = threadIdx.x, ty = threadIdx.y;
#pragma unroll
    for (int j = 0; j < 4; j++)
        tile[ty + 8 * j][tx] = wd.s[(size_t)(y0 + ty + 8 * j) * n + x0 + tx];
    __syncthreads();
#pragma unroll
    for (int j = 0; j < 4; j++)
        wd.d[(size_t)(x0 + ty + 8 * j) * n + y0 + tx] = f2bf(tile[tx][ty + 8 * j] * wd.sc);
}

// ---------------- f0 = [s, |v|] as bf16 ----------------
__global__ void prep_f0(const float* __restrict__ x, u16* __restrict__ f0) {
    int n = blockIdx.x, u = threadIdx.x;
    const float* xr = x + (size_t)n * 1024;
    float s = xr[u];
    float v0 = xr[256 + 3 * u], v1 = xr[256 + 3 * u + 1], v2 = xr[256 + 3 * u + 2];
    float nv = sqrtf(v0 * v0 + v1 * v1 + v2 * v2 + 1e-12f);
    f0[(size_t)n * 512 + u] = f2bf(s);
    f0[(size_t)n * 512 + 256 + u] = f2bf(nv);
}

// ---------------- GEMM: C = act(A @ Bt^T + bias) ----------------
// A modes: 0 = plain bf16 [M,lda]; 1 = gated from f32 interleaved x (plane zi);
//          2 = gated from bf16 planar src (plane zi, plane stride xps)
__global__ __launch_bounds__(256)
void gemm_k(const u16* __restrict__ Ap, int lda,
            const void* __restrict__ xsrc, long xps,
            const u16* __restrict__ gp,
            const u16* __restrict__ Bt,
            const float* __restrict__ bias,
            u16* __restrict__ C, int ldc, long cps,
            int K, int mode, int act)
{
    const int tid = threadIdx.x;
    const int lane = tid & 63;
    const int wid = tid >> 6;
    const int wr = wid >> 1, wc = wid & 1;
    const long row0 = (long)blockIdx.x * 128;
    const int n0 = blockIdx.y * 128;
    const int zi = blockIdx.z;
    const int lr = lane & 15, hk = lane >> 4;

    __shared__ __align__(16) u16 Asm[128 * 64];
    __shared__ __align__(16) u16 Bsm[128 * 64];

    f32x4 acc[4][4];
#pragma unroll
    for (int m = 0; m < 4; m++)
#pragma unroll
        for (int n = 0; n < 4; n++) acc[m][n] = (f32x4){0.f, 0.f, 0.f, 0.f};

    for (int kt = 0; kt < K; kt += 64) {
        // ---- stage B tile [128 cols][64 k] via global_load_lds ----
#pragma unroll
        for (int it = 0; it < 4; ++it) {
            int idx = it * 256 + tid;
            int r = idx >> 3;
            int c8 = (idx & 7) * 8;
            const u16* g = Bt + (size_t)(n0 + r) * K + kt + c8;
            u16* l = &Bsm[(size_t)(it * 256 + (tid & 192)) * 8];
            gload_lds16(g, l);
        }
        // ---- stage A tile [128 rows][64 k] ----
        if (mode == 0) {
#pragma unroll
            for (int it = 0; it < 4; ++it) {
                int idx = it * 256 + tid;
                int r = idx >> 3;
                int c8 = (idx & 7) * 8;
                const u16* g = Ap + (size_t)(row0 + r) * lda + kt + c8;
                u16* l = &Asm[(size_t)(it * 256 + (tid & 192)) * 8];
                gload_lds16(g, l);
            }
        } else {
#pragma unroll
            for (int it = 0; it < 4; ++it) {
                int idx = it * 256 + tid;
                int r = idx >> 3;
                int c8 = (idx & 7) * 8;
                long row = row0 + r;
                int u = kt + c8;
                union { short8 v; u16 s[8]; } gg, pk;
                gg.v = *(const short8*)(gp + (size_t)row * 512 + 256 + u);
                float vv[8];
                if (mode == 1) {
                    const float* xv = (const float*)xsrc + (size_t)row * 1024 + 256;
#pragma unroll
                    for (int j = 0; j < 8; j++) vv[j] = xv[3 * (u + j) + zi];
                } else {
                    union { short8 v; u16 s[8]; } tu;
                    tu.v = *(const short8*)((const u16*)xsrc + (size_t)zi * xps + (size_t)row * 256 + u);
#pragma unroll
                    for (int j = 0; j < 8; j++) vv[j] = bf2f(tu.s[j]);
                }
#pragma unroll
                for (int j = 0; j < 8; j++) pk.s[j] = f2bf(vv[j] * bf2f(gg.s[j]));
                *(short8*)&Asm[(size_t)idx * 8] = pk.v;
            }
        }
        asm volatile("s_waitcnt vmcnt(0)" ::: "memory");
        __syncthreads();

        // ---- compute ----
#pragma unroll
        for (int kk = 0; kk < 2; ++kk) {
            short8 a[4], b[4];
#pragma unroll
            for (int m = 0; m < 4; m++)
                a[m] = *(const short8*)&Asm[(size_t)(wr * 64 + m * 16 + lr) * 64 + kk * 32 + hk * 8];
#pragma unroll
            for (int n = 0; n < 4; n++)
                b[n] = *(const short8*)&Bsm[(size_t)(wc * 64 + n * 16 + lr) * 64 + kk * 32 + hk * 8];
#pragma unroll
            for (int m = 0; m < 4; m++)
#pragma unroll
                for (int n = 0; n < 4; n++)
                    acc[m][n] = __builtin_amdgcn_mfma_f32_16x16x32_bf16(a[m], b[n], acc[m][n], 0, 0, 0);
        }
        __syncthreads();
    }

    // ---- epilogue ----
#pragma unroll
    for (int n = 0; n < 4; n++) {
        int col = n0 + wc * 64 + n * 16 + lr;
        float bv = bias ? bias[col] : 0.0f;
#pragma unroll
        for (int m = 0; m < 4; m++) {
#pragma unroll
            for (int j = 0; j < 4; j++) {
                long row = row0 + wr * 64 + m * 16 + hk * 4 + j;
                float v = acc[m][n][j] + bv;
                if (act) v = v * (1.0f / (1.0f + __expf(-v)));
                C[(size_t)zi * cps + (size_t)row * ldc + col] = f2bf(v);
            }
        }
    }
}

// ---------------- tensor product + residual -> f0', tv planes ----------------
__global__ void tp_res(const u16* __restrict__ xl, const u16* __restrict__ xr,
                       const float* __restrict__ x, const float* __restrict__ tpw,
                       u16* __restrict__ f0p, u16* __restrict__ tv, long ps)
{
    int n = blockIdx.x, u = threadIdx.x;
    size_t o = (size_t)n * 256 + u;
    float s1 = bf2f(xl[o]);
    float a1x = bf2f(xl[ps + o]), a1y = bf2f(xl[2 * ps + o]), a1z = bf2f(xl[3 * ps + o]);
    float s2 = bf2f(xr[o]);
    float b1x = bf2f(xr[ps + o]), b1y = bf2f(xr[2 * ps + o]), b1z = bf2f(xr[3 * ps + o]);
    float w0 = tpw[u], w1 = tpw[256 + u], w2 = tpw[512 + u], w3 = tpw[768 + u], w4 = tpw[1024 + u];

    float dot = a1x * b1x + a1y * b1y + a1z * b1z;
    float cx = a1y * b1z - a1z * b1y;
    float cy = a1z * b1x - a1x * b1z;
    float cz = a1x * b1y - a1y * b1x;

    const float* xrow = x + (size_t)n * 1024;
    float out0 = A0C * (w0 * s1 * s2 + w3 * INV3C * dot) + xrow[u];
    float ox = A1C * (INV3C * (w1 * s1 * b1x + w2 * s2 * a1x) + INV6C * w4 * cx) + xrow[256 + 3 * u];
    float oy = A1C * (INV3C * (w1 * s1 * b1y + w2 * s2 * a1y) + INV6C * w4 * cy) + xrow[256 + 3 * u + 1];
    float oz = A1C * (INV3C * (w1 * s1 * b1z + w2 * s2 * a1z) + INV6C * w4 * cz) + xrow[256 + 3 * u + 2];

    float nv = sqrtf(ox * ox + oy * oy + oz * oz + 1e-12f);
    f0p[(size_t)n * 512 + u] = f2bf(out0);
    f0p[(size_t)n * 512 + 256 + u] = f2bf(nv);
    tv[o] = f2bf(ox);
    tv[ps + o] = f2bf(oy);
    tv[2 * ps + o] = f2bf(oz);
}

// ---------------- repack planar -> interleaved + old_fii ----------------
__global__ void repack(const u16* __restrict__ outp, const float* __restrict__ old,
                       float* __restrict__ out, long ps)
{
    long t = (long)blockIdx.x * 256 + threadIdx.x;
    long n = t >> 10;
    int c = (int)(t & 1023);
    float add;
    if (c < 256) {
        add = bf2f(outp[n * 256 + c]);
    } else {
        int cc = c - 256;
        int w = cc / 3;
        int i = cc - 3 * w;
        add = bf2f(outp[(size_t)(1 + i) * ps + n * 256 + w]);
    }
    out[t] = old[t] + add;
}

// weight offsets (bf16 elements) in ws
enum {
    OFF_ng1w1 = 0,        OFF_ng1w2 = 262144,
    OFF_ng2w1 = 524288,   OFF_ng2w2 = 786432,
    OFF_ngow1 = 1048576,  OFF_ngow2 = 1310720,
    OFF_l1w0 = 1572864,   OFF_l1w1 = 1638400,
    OFF_l2w0 = 1703936,   OFF_l2w1 = 1769472,
    OFF_l3w0 = 1835008,   OFF_l3w1 = 1900544
};

extern "C" void kernel_launch(void* const* d_in, const int* in_sizes, int n_in,
                              void* d_out, int out_size, void* d_ws, size_t ws_size,
                              hipStream_t stream) {
    const float* x      = (const float*)d_in[0];
    const float* oldf   = (const float*)d_in[1];
    const float* ng1_w1 = (const float*)d_in[2];
    const float* ng1_b1 = (const float*)d_in[3];
    const float* ng1_w2 = (const float*)d_in[4];
    const float* ng1_b2 = (const float*)d_in[5];
    const float* ng2_w1 = (const float*)d_in[6];
    const float* ng2_b1 = (const float*)d_in[7];
    const float* ng2_w2 = (const float*)d_in[8];
    const float* ng2_b2 = (const float*)d_in[9];
    const float* ngo_w1 = (const float*)d_in[10];
    const float* ngo_b1 = (const float*)d_in[11];
    const float* ngo_w2 = (const float*)d_in[12];
    const float* ngo_b2 = (const float*)d_in[13];
    const float* l1_w0  = (const float*)d_in[14];
    const float* l1_b0  = (const float*)d_in[15];
    const float* l1_w1  = (const float*)d_in[16];
    const float* l2_w0  = (const float*)d_in[17];
    const float* l2_b0  = (const float*)d_in[18];
    const float* l2_w1  = (const float*)d_in[19];
    const float* l3_w0  = (const float*)d_in[20];
    const float* l3_b0  = (const float*)d_in[21];
    const float* l3_w1  = (const float*)d_in[22];
    const float* tpw    = (const float*)d_in[23];

    u16* wts = (u16*)d_ws;

    // --- weight cvt (one dispatch) ---
    WArgs wa;
    wa.w[0]  = { ng1_w1, wts + OFF_ng1w1, 512, 1.0f };
    wa.w[1]  = { ng1_w2, wts + OFF_ng1w2, 512, 1.0f };
    wa.w[2]  = { ng2_w1, wts + OFF_ng2w1, 512, 1.0f };
    wa.w[3]  = { ng2_w2, wts + OFF_ng2w2, 512, 1.0f };
    wa.w[4]  = { ngo_w1, wts + OFF_ngow1, 512, 1.0f };
    wa.w[5]  = { ngo_w2, wts + OFF_ngow2, 512, 1.0f };
    wa.w[6]  = { l1_w0, wts + OFF_l1w0, 256, 0.0625f };
    wa.w[7]  = { l1_w1, wts + OFF_l1w1, 256, 0.0625f };
    wa.w[8]  = { l2_w0, wts + OFF_l2w0, 256, 0.0625f };
    wa.w[9]  = { l2_w1, wts + OFF_l2w1, 256, 0.0625f };
    wa.w[10] = { l3_w0, wts + OFF_l3w0, 256, 0.0625f };
    wa.w[11] = { l3_w1, wts + OFF_l3w1, 256, 0.0625f };
    cvt_weights<<<dim3(16, 16, 12), dim3(32, 8), 0, stream>>>(wa);

    long Nn = (long)in_sizes[0] / 1024;

    // pick chunk count so ws fits: peak = 4MiB + Nc*8704 bytes
    int c = 1;
    while (c < 256 && (unsigned long long)(4ULL << 20) + (unsigned long long)(Nn / c) * 8704ULL > (unsigned long long)ws_size)
        c <<= 1;
    long Nc = Nn / c;

    char* wsb = (char*)d_ws;
    u16* F0 = (u16*)(wsb + (4 << 20));
    u16* H  = F0 + (size_t)Nc * 512;
    u16* G  = H + (size_t)Nc * 512;
    u16* XL = G + (size_t)Nc * 512;
    u16* XR = XL + (size_t)Nc * 1024;
    u16* TV = XR + (size_t)Nc * 1024;
    long ps = Nc * 256;
    u16* OUTP = XL; // reuse (xl dead after tp_res)

    dim3 blk(256);
    int mt = (int)(Nc / 128);

    for (int ch = 0; ch < c; ++ch) {
        const float* xk  = x + (size_t)ch * Nc * 1024;
        const float* ok  = oldf + (size_t)ch * Nc * 1024;
        float* outk = (float*)d_out + (size_t)ch * Nc * 1024;

        prep_f0<<<(int)Nc, 256, 0, stream>>>(xk, F0);

        // ng1 MLP: h = silu(f0@w1+b1); g = h@w2+b2
        gemm_k<<<dim3(mt, 4, 1), blk, 0, stream>>>(F0, 512, nullptr, 0, nullptr,
            wts + OFF_ng1w1, ng1_b1, H, 512, 0, 512, 0, 1);
        gemm_k<<<dim3(mt, 4, 1), blk, 0, stream>>>(H, 512, nullptr, 0, nullptr,
            wts + OFF_ng1w2, ng1_b2, G, 512, 0, 512, 0, 0);
        // lin1 -> XL (planar: s, v0, v1, v2)
        gemm_k<<<dim3(mt, 2, 1), blk, 0, stream>>>(G, 512, nullptr, 0, nullptr,
            wts + OFF_l1w0, l1_b0, XL, 256, 0, 256, 0, 0);
        gemm_k<<<dim3(mt, 2, 3), blk, 0, stream>>>(nullptr, 0, xk, 0, G,
            wts + OFF_l1w1, nullptr, XL + ps, 256, ps, 256, 1, 0);

        // ng2 MLP
        gemm_k<<<dim3(mt, 4, 1), blk, 0, stream>>>(F0, 512, nullptr, 0, nullptr,
            wts + OFF_ng2w1, ng2_b1, H, 512, 0, 512, 0, 1);
        gemm_k<<<dim3(mt, 4, 1), blk, 0, stream>>>(H, 512, nullptr, 0, nullptr,
            wts + OFF_ng2w2, ng2_b2, G, 512, 0, 512, 0, 0);
        // lin2 -> XR
        gemm_k<<<dim3(mt, 2, 1), blk, 0, stream>>>(G, 512, nullptr, 0, nullptr,
            wts + OFF_l2w0, l2_b0, XR, 256, 0, 256, 0, 0);
        gemm_k<<<dim3(mt, 2, 3), blk, 0, stream>>>(nullptr, 0, xk, 0, G,
            wts + OFF_l2w1, nullptr, XR + ps, 256, ps, 256, 1, 0);

        // tensor product + residual -> f0' (into F0), tv planes
        tp_res<<<(int)Nc, 256, 0, stream>>>(XL, XR, xk, tpw, F0, TV, ps);

        // ngo MLP
        gemm_k<<<dim3(mt, 4, 1), blk, 0, stream>>>(F0, 512, nullptr, 0, nullptr,
            wts + OFF_ngow1, ngo_b1, H, 512, 0, 512, 0, 1);
        gemm_k<<<dim3(mt, 4, 1), blk, 0, stream>>>(H, 512, nullptr, 0, nullptr,
            wts + OFF_ngow2, ngo_b2, G, 512, 0, 512, 0, 0);
        // lin3 -> OUTP planar (reuses XL region)
        gemm_k<<<dim3(mt, 2, 1), blk, 0, stream>>>(G, 512, nullptr, 0, nullptr,
            wts + OFF_l3w0, l3_b0, OUTP, 256, 0, 256, 0, 0);
        gemm_k<<<dim3(mt, 2, 3), blk, 0, stream>>>(nullptr, 0, TV, ps, G,
            wts + OFF_l3w1, nullptr, OUTP + ps, 256, ps, 256, 2, 0);

        // repack + old_fii -> out (f32 interleaved)
        repack<<<(int)(Nc * 4), 256, 0, stream>>>(OUTP, ok, outk, ps);
    }
}

// Round 2
// 677.948 us; speedup vs baseline: 1.1690x; 1.1690x over previous
//
#include <hip/hip_runtime.h>
#include <stdint.h>
#include <math.h>

typedef unsigned short u16;
typedef __attribute__((ext_vector_type(8))) short short8;
typedef __attribute__((ext_vector_type(4))) float f32x4;

#define A0C 0.44721359549995793f
#define A1C 0.77459666924148340f
#define INV3C 0.57735026918962584f
#define INV6C 0.40824829046386302f

__device__ __forceinline__ float bf2f(u16 u) {
    unsigned v = ((unsigned)u) << 16; float f; __builtin_memcpy(&f, &v, 4); return f;
}
__device__ __forceinline__ u16 f2bf(float f) {
    unsigned u; __builtin_memcpy(&u, &f, 4);
    u += 0x7fffu + ((u >> 16) & 1u);
    return (u16)(u >> 16);
}

__device__ __forceinline__ void gload_lds16(const void* g, void* l) {
    __builtin_amdgcn_global_load_lds((const __attribute__((address_space(1))) unsigned*)g,
                                     (__attribute__((address_space(3))) unsigned*)l, 16, 0, 0);
}

// ---------------- weight transpose + bf16 convert ----------------
struct WDesc { const float* s; u16* d; int n; float sc; };
struct WArgs { WDesc w[12]; };

__global__ void cvt_weights(WArgs args) {
    WDesc wd = args.w[blockIdx.z];
    int n = wd.n;
    int x0 = blockIdx.x * 32, y0 = blockIdx.y * 32;
    if (x0 >= n || y0 >= n) return;
    __shared__ float tile[32][33];
    int tx = threadIdx.x, ty = threadIdx.y;
#pragma unroll
    for (int j = 0; j < 4; j++)
        tile[ty + 8 * j][tx] = wd.s[(size_t)(y0 + ty + 8 * j) * n + x0 + tx];
    __syncthreads();
#pragma unroll
    for (int j = 0; j < 4; j++)
        wd.d[(size_t)(x0 + ty + 8 * j) * n + y0 + tx] = f2bf(tile[tx][ty + 8 * j] * wd.sc);
}

// ---------------- prep: f0 = [s,|v|] bf16, XV = planar bf16 vector planes ----------------
__global__ void prep_f0(const float* __restrict__ x, u16* __restrict__ f0,
                        u16* __restrict__ xv, long ps) {
    int n = blockIdx.x, u = threadIdx.x;
    const float* xr = x + (size_t)n * 1024;
    float s = xr[u];
    float v0 = xr[256 + 3 * u], v1 = xr[256 + 3 * u + 1], v2 = xr[256 + 3 * u + 2];
    float nv = sqrtf(v0 * v0 + v1 * v1 + v2 * v2 + 1e-12f);
    size_t o = (size_t)n * 256 + u;
    f0[(size_t)n * 512 + u] = f2bf(s);
    f0[(size_t)n * 512 + 256 + u] = f2bf(nv);
    xv[o] = f2bf(v0);
    xv[ps + o] = f2bf(v1);
    xv[2 * ps + o] = f2bf(v2);
}

// ---------------- GEMM: C = act(A @ Bt^T + bias) ----------------
// tile 128x256, BK=64, 512 threads (8 waves: 2 row x 4 col)
// mode 0: A = plain bf16 [M, lda]
// mode 2: A = xsrc plane zi (bf16 planar, stride xps) * gate gp[row*512+256+u]
__global__ __launch_bounds__(512)
void gemm_k(const u16* __restrict__ Ap, int lda,
            const u16* __restrict__ xsrc, long xps,
            const u16* __restrict__ gp,
            const u16* __restrict__ Bt,
            const float* __restrict__ bias,
            u16* __restrict__ C, int ldc, long cps,
            int K, int mode, int act, int nshift)
{
    const int tid = threadIdx.x;
    const int lane = tid & 63;
    const int wid = tid >> 6;
    const int wr = wid >> 2, wc = wid & 3;
    const int lr = lane & 15, hk = lane >> 4;

    // bijective XCD-chunked swizzle (n-fastest decode)
    int nwg = gridDim.x;
    int lid = blockIdx.x;
    int wg;
    if ((nwg & 7) == 0) { int q = nwg >> 3; wg = (lid & 7) * q + (lid >> 3); }
    else wg = lid;
    const long row0 = (long)(wg >> nshift) * 128;
    const int n0 = (wg & ((1 << nshift) - 1)) * 256;
    const int zi = blockIdx.y;

    __shared__ __align__(16) u16 Asm[128 * 64];
    __shared__ __align__(16) u16 Bsm[256 * 64];

    f32x4 acc[4][4];
#pragma unroll
    for (int m = 0; m < 4; m++)
#pragma unroll
        for (int n = 0; n < 4; n++) acc[m][n] = (f32x4){0.f, 0.f, 0.f, 0.f};

    for (int kt = 0; kt < K; kt += 64) {
        // ---- stage B tile [256 cols][64 k] ----
#pragma unroll
        for (int it = 0; it < 4; ++it) {
            int idx = it * 512 + tid;
            int r = idx >> 3;
            int c8 = (idx & 7) * 8;
            const u16* g = Bt + (size_t)(n0 + r) * K + kt + c8;
            u16* l = &Bsm[(size_t)(it * 512 + (tid & 0x1C0)) * 8];
            gload_lds16(g, l);
        }
        // ---- stage A tile [128 rows][64 k] ----
        if (mode == 0) {
#pragma unroll
            for (int it = 0; it < 2; ++it) {
                int idx = it * 512 + tid;
                int r = idx >> 3;
                int c8 = (idx & 7) * 8;
                const u16* g = Ap + (size_t)(row0 + r) * lda + kt + c8;
                u16* l = &Asm[(size_t)(it * 512 + (tid & 0x1C0)) * 8];
                gload_lds16(g, l);
            }
        } else {
#pragma unroll
            for (int it = 0; it < 2; ++it) {
                int idx = it * 512 + tid;
                int r = idx >> 3;
                int c8 = (idx & 7) * 8;
                long row = row0 + r;
                int u = kt + c8;
                union { short8 v; u16 s[8]; } gg, tu, pk;
                gg.v = *(const short8*)(gp + (size_t)row * 512 + 256 + u);
                tu.v = *(const short8*)(xsrc + (size_t)zi * xps + (size_t)row * 256 + u);
#pragma unroll
                for (int j = 0; j < 8; j++) pk.s[j] = f2bf(bf2f(tu.s[j]) * bf2f(gg.s[j]));
                *(short8*)&Asm[(size_t)idx * 8] = pk.v;
            }
        }
        asm volatile("s_waitcnt vmcnt(0)" ::: "memory");
        __syncthreads();

        // ---- compute ----
#pragma unroll
        for (int kk = 0; kk < 2; ++kk) {
            short8 a[4], b[4];
#pragma unroll
            for (int m = 0; m < 4; m++)
                a[m] = *(const short8*)&Asm[(size_t)(wr * 64 + m * 16 + lr) * 64 + kk * 32 + hk * 8];
#pragma unroll
            for (int n = 0; n < 4; n++)
                b[n] = *(const short8*)&Bsm[(size_t)(wc * 64 + n * 16 + lr) * 64 + kk * 32 + hk * 8];
#pragma unroll
            for (int m = 0; m < 4; m++)
#pragma unroll
                for (int n = 0; n < 4; n++)
                    acc[m][n] = __builtin_amdgcn_mfma_f32_16x16x32_bf16(a[m], b[n], acc[m][n], 0, 0, 0);
        }
        __syncthreads();
    }

    // ---- epilogue ----
#pragma unroll
    for (int n = 0; n < 4; n++) {
        int col = n0 + wc * 64 + n * 16 + lr;
        float bv = bias ? bias[col] : 0.0f;
#pragma unroll
        for (int m = 0; m < 4; m++) {
#pragma unroll
            for (int j = 0; j < 4; j++) {
                long row = row0 + wr * 64 + m * 16 + hk * 4 + j;
                float v = acc[m][n][j] + bv;
                if (act) v = v * (1.0f / (1.0f + __expf(-v)));
                C[(size_t)zi * cps + (size_t)row * ldc + col] = f2bf(v);
            }
        }
    }
}

// ---------------- tensor product + residual -> f0', tv planes ----------------
// NOTE: tv aliases xr_+ps (overwrites XR vector planes); f0 is read (residual
// scalars) then overwritten. All reads happen before writes; no cross-thread
// hazard (element-wise bijection). No __restrict__ on aliased pointers.
__global__ void tp_res(const u16* __restrict__ xl, const u16* xr_,
                       const float* __restrict__ tpw, const u16* __restrict__ xv,
                       u16* f0, u16* tv, long ps)
{
    int n = blockIdx.x, u = threadIdx.x;
    size_t o = (size_t)n * 256 + u;
    float s1 = bf2f(xl[o]);
    float a1x = bf2f(xl[ps + o]), a1y = bf2f(xl[2 * ps + o]), a1z = bf2f(xl[3 * ps + o]);
    float s2 = bf2f(xr_[o]);
    float b1x = bf2f(xr_[ps + o]), b1y = bf2f(xr_[2 * ps + o]), b1z = bf2f(xr_[3 * ps + o]);
    float xs = bf2f(f0[(size_t)n * 512 + u]);
    float rx = bf2f(xv[o]), ry = bf2f(xv[ps + o]), rz = bf2f(xv[2 * ps + o]);
    float w0 = tpw[u], w1 = tpw[256 + u], w2 = tpw[512 + u], w3 = tpw[768 + u], w4 = tpw[1024 + u];

    float dot = a1x * b1x + a1y * b1y + a1z * b1z;
    float cx = a1y * b1z - a1z * b1y;
    float cy = a1z * b1x - a1x * b1z;
    float cz = a1x * b1y - a1y * b1x;

    float out0 = A0C * (w0 * s1 * s2 + w3 * INV3C * dot) + xs;
    float ox = A1C * (INV3C * (w1 * s1 * b1x + w2 * s2 * a1x) + INV6C * w4 * cx) + rx;
    float oy = A1C * (INV3C * (w1 * s1 * b1y + w2 * s2 * a1y) + INV6C * w4 * cy) + ry;
    float oz = A1C * (INV3C * (w1 * s1 * b1z + w2 * s2 * a1z) + INV6C * w4 * cz) + rz;

    float nv = sqrtf(ox * ox + oy * oy + oz * oz + 1e-12f);
    f0[(size_t)n * 512 + u] = f2bf(out0);
    f0[(size_t)n * 512 + 256 + u] = f2bf(nv);
    tv[o] = f2bf(ox);
    tv[ps + o] = f2bf(oy);
    tv[2 * ps + o] = f2bf(oz);
}

// ---------------- repack planar -> interleaved + old_fii ----------------
__global__ void repack(const u16* __restrict__ outp, const float* __restrict__ old,
                       float* __restrict__ out, long ps)
{
    long t = (long)blockIdx.x * 256 + threadIdx.x;
    long n = t >> 10;
    int c = (int)(t & 1023);
    float add;
    if (c < 256) {
        add = bf2f(outp[n * 256 + c]);
    } else {
        int cc = c - 256;
        int w = cc / 3;
        int i = cc - 3 * w;
        add = bf2f(outp[(size_t)(1 + i) * ps + n * 256 + w]);
    }
    out[t] = old[t] + add;
}

// weight offsets (bf16 elements) in ws
enum {
    OFF_ng1w1 = 0,        OFF_ng1w2 = 262144,
    OFF_ng2w1 = 524288,   OFF_ng2w2 = 786432,
    OFF_ngow1 = 1048576,  OFF_ngow2 = 1310720,
    OFF_l1w0 = 1572864,   OFF_l1w1 = 1638400,
    OFF_l2w0 = 1703936,   OFF_l2w1 = 1769472,
    OFF_l3w0 = 1835008,   OFF_l3w1 = 1900544
};

extern "C" void kernel_launch(void* const* d_in, const int* in_sizes, int n_in,
                              void* d_out, int out_size, void* d_ws, size_t ws_size,
                              hipStream_t stream) {
    const float* x      = (const float*)d_in[0];
    const float* oldf   = (const float*)d_in[1];
    const float* ng1_w1 = (const float*)d_in[2];
    const float* ng1_b1 = (const float*)d_in[3];
    const float* ng1_w2 = (const float*)d_in[4];
    const float* ng1_b2 = (const float*)d_in[5];
    const float* ng2_w1 = (const float*)d_in[6];
    const float* ng2_b1 = (const float*)d_in[7];
    const float* ng2_w2 = (const float*)d_in[8];
    const float* ng2_b2 = (const float*)d_in[9];
    const float* ngo_w1 = (const float*)d_in[10];
    const float* ngo_b1 = (const float*)d_in[11];
    const float* ngo_w2 = (const float*)d_in[12];
    const float* ngo_b2 = (const float*)d_in[13];
    const float* l1_w0  = (const float*)d_in[14];
    const float* l1_b0  = (const float*)d_in[15];
    const float* l1_w1  = (const float*)d_in[16];
    const float* l2_w0  = (const float*)d_in[17];
    const float* l2_b0  = (const float*)d_in[18];
    const float* l2_w1  = (const float*)d_in[19];
    const float* l3_w0  = (const float*)d_in[20];
    const float* l3_b0  = (const float*)d_in[21];
    const float* l3_w1  = (const float*)d_in[22];
    const float* tpw    = (const float*)d_in[23];

    u16* wts = (u16*)d_ws;

    WArgs wa;
    wa.w[0]  = { ng1_w1, wts + OFF_ng1w1, 512, 1.0f };
    wa.w[1]  = { ng1_w2, wts + OFF_ng1w2, 512, 1.0f };
    wa.w[2]  = { ng2_w1, wts + OFF_ng2w1, 512, 1.0f };
    wa.w[3]  = { ng2_w2, wts + OFF_ng2w2, 512, 1.0f };
    wa.w[4]  = { ngo_w1, wts + OFF_ngow1, 512, 1.0f };
    wa.w[5]  = { ngo_w2, wts + OFF_ngow2, 512, 1.0f };
    wa.w[6]  = { l1_w0, wts + OFF_l1w0, 256, 0.0625f };
    wa.w[7]  = { l1_w1, wts + OFF_l1w1, 256, 0.0625f };
    wa.w[8]  = { l2_w0, wts + OFF_l2w0, 256, 0.0625f };
    wa.w[9]  = { l2_w1, wts + OFF_l2w1, 256, 0.0625f };
    wa.w[10] = { l3_w0, wts + OFF_l3w0, 256, 0.0625f };
    wa.w[11] = { l3_w1, wts + OFF_l3w1, 256, 0.0625f };
    cvt_weights<<<dim3(16, 16, 12), dim3(32, 8), 0, stream>>>(wa);

    long Nn = (long)in_sizes[0] / 1024;

    // chunking so ws fits: peak = 4MiB + Nc*8704 bytes
    int c = 1;
    while (c < 256 && (unsigned long long)(4ULL << 20) + (unsigned long long)(Nn / c) * 8704ULL > (unsigned long long)ws_size)
        c <<= 1;
    long Nc = Nn / c;

    char* wsb = (char*)d_ws;
    u16* F0 = (u16*)(wsb + (4 << 20));       // [Nc,512]
    u16* H  = F0 + (size_t)Nc * 512;         // [Nc,512]
    u16* G  = H + (size_t)Nc * 512;          // [Nc,512]
    u16* XV = G + (size_t)Nc * 512;          // [3][Nc,256]
    u16* XL = XV + (size_t)Nc * 768;         // [4][Nc,256]
    u16* XR = XL + (size_t)Nc * 1024;        // [4][Nc,256]
    long ps = Nc * 256;
    u16* TV   = XR + ps;                     // aliases XR vector planes
    u16* OUTP = XL;                          // aliases XL (dead after tp_res)

    dim3 blk(512);
    int mt = (int)(Nc / 128);

    for (int ch = 0; ch < c; ++ch) {
        const float* xk  = x + (size_t)ch * Nc * 1024;
        const float* ok  = oldf + (size_t)ch * Nc * 1024;
        float* outk = (float*)d_out + (size_t)ch * Nc * 1024;

        prep_f0<<<(int)Nc, 256, 0, stream>>>(xk, F0, XV, ps);

        // ng1 MLP
        gemm_k<<<dim3(mt * 2, 1), blk, 0, stream>>>(F0, 512, nullptr, 0, nullptr,
            wts + OFF_ng1w1, ng1_b1, H, 512, 0, 512, 0, 1, 1);
        gemm_k<<<dim3(mt * 2, 1), blk, 0, stream>>>(H, 512, nullptr, 0, nullptr,
            wts + OFF_ng1w2, ng1_b2, G, 512, 0, 512, 0, 0, 1);
        // lin1: scalar + gated vector planes -> XL
        gemm_k<<<dim3(mt, 1), blk, 0, stream>>>(G, 512, nullptr, 0, nullptr,
            wts + OFF_l1w0, l1_b0, XL, 256, 0, 256, 0, 0, 0);
        gemm_k<<<dim3(mt, 3), blk, 0, stream>>>(nullptr, 0, XV, ps, G,
            wts + OFF_l1w1, nullptr, XL + ps, 256, ps, 256, 2, 0, 0);

        // ng2 MLP
        gemm_k<<<dim3(mt * 2, 1), blk, 0, stream>>>(F0, 512, nullptr, 0, nullptr,
            wts + OFF_ng2w1, ng2_b1, H, 512, 0, 512, 0, 1, 1);
        gemm_k<<<dim3(mt * 2, 1), blk, 0, stream>>>(H, 512, nullptr, 0, nullptr,
            wts + OFF_ng2w2, ng2_b2, G, 512, 0, 512, 0, 0, 1);
        // lin2 -> XR
        gemm_k<<<dim3(mt, 1), blk, 0, stream>>>(G, 512, nullptr, 0, nullptr,
            wts + OFF_l2w0, l2_b0, XR, 256, 0, 256, 0, 0, 0);
        gemm_k<<<dim3(mt, 3), blk, 0, stream>>>(nullptr, 0, XV, ps, G,
            wts + OFF_l2w1, nullptr, XR + ps, 256, ps, 256, 2, 0, 0);

        // tensor product + residual -> F0', TV (in place of XR vector planes)
        tp_res<<<(int)Nc, 256, 0, stream>>>(XL, XR, tpw, XV, F0, TV, ps);

        // ngo MLP
        gemm_k<<<dim3(mt * 2, 1), blk, 0, stream>>>(F0, 512, nullptr, 0, nullptr,
            wts + OFF_ngow1, ngo_b1, H, 512, 0, 512, 0, 1, 1);
        gemm_k<<<dim3(mt * 2, 1), blk, 0, stream>>>(H, 512, nullptr, 0, nullptr,
            wts + OFF_ngow2, ngo_b2, G, 512, 0, 512, 0, 0, 1);
        // lin3 -> OUTP planar (reuses XL)
        gemm_k<<<dim3(mt, 1), blk, 0, stream>>>(G, 512, nullptr, 0, nullptr,
            wts + OFF_l3w0, l3_b0, OUTP, 256, 0, 256, 0, 0, 0);
        gemm_k<<<dim3(mt, 3), blk, 0, stream>>>(nullptr, 0, TV, ps, G,
            wts + OFF_l3w1, nullptr, OUTP + ps, 256, ps, 256, 2, 0, 0);

        // repack + old_fii -> out
        repack<<<(int)(Nc * 4), 256, 0, stream>>>(OUTP, ok, outk, ps);
    }
}

// Round 3
// 624.369 us; speedup vs baseline: 1.2693x; 1.0858x over previous
//
#include <hip/hip_runtime.h>
#include <stdint.h>
#include <math.h>

typedef unsigned short u16;
typedef __attribute__((ext_vector_type(8))) short short8;
typedef __attribute__((ext_vector_type(4))) float f32x4;

#define A0C 0.44721359549995793f
#define A1C 0.77459666924148340f
#define INV3C 0.57735026918962584f
#define INV6C 0.40824829046386302f

__device__ __forceinline__ float bf2f(u16 u) {
    unsigned v = ((unsigned)u) << 16; float f; __builtin_memcpy(&f, &v, 4); return f;
}
__device__ __forceinline__ u16 f2bf(float f) {
    unsigned u; __builtin_memcpy(&u, &f, 4);
    u += 0x7fffu + ((u >> 16) & 1u);
    return (u16)(u >> 16);
}

__device__ __forceinline__ void gload_lds16(const void* g, void* l) {
    __builtin_amdgcn_global_load_lds((const __attribute__((address_space(1))) unsigned*)g,
                                     (__attribute__((address_space(3))) unsigned*)l, 16, 0, 0);
}

// ---------------- weight transpose + bf16 convert ----------------
struct WDesc { const float* s; u16* d; int n; float sc; };
struct WArgs { WDesc w[12]; };

__global__ void cvt_weights(WArgs args) {
    WDesc wd = args.w[blockIdx.z];
    int n = wd.n;
    int x0 = blockIdx.x * 32, y0 = blockIdx.y * 32;
    if (x0 >= n || y0 >= n) return;
    __shared__ float tile[32][33];
    int tx = threadIdx.x, ty = threadIdx.y;
#pragma unroll
    for (int j = 0; j < 4; j++)
        tile[ty + 8 * j][tx] = wd.s[(size_t)(y0 + ty + 8 * j) * n + x0 + tx];
    __syncthreads();
#pragma unroll
    for (int j = 0; j < 4; j++)
        wd.d[(size_t)(x0 + ty + 8 * j) * n + y0 + tx] = f2bf(tile[tx][ty + 8 * j] * wd.sc);
}

// ---------------- bias pack ----------------
struct BDesc { const float* s; float* d; int n; };
struct BArgs { BDesc b[9]; };
__global__ void pack_bias(BArgs a) {
    BDesc b = a.b[blockIdx.x];
    for (int i = threadIdx.x; i < b.n; i += 256) b.d[i] = b.s[i];
}

// ---------------- prep: f0 = [s,|v|] bf16, XV planar bf16 ----------------
__global__ void prep_f0(const float* __restrict__ x, u16* __restrict__ f0,
                        u16* __restrict__ xv, long ps) {
    __shared__ float row[1024];
    int n = blockIdx.x, u = threadIdx.x;
    const float4* xr = (const float4*)(x + (size_t)n * 1024);
    float4 v4 = xr[u];
    row[4 * u] = v4.x; row[4 * u + 1] = v4.y; row[4 * u + 2] = v4.z; row[4 * u + 3] = v4.w;
    __syncthreads();
    float s = row[u];
    float v0 = row[256 + 3 * u], v1 = row[256 + 3 * u + 1], v2 = row[256 + 3 * u + 2];
    float nv = sqrtf(v0 * v0 + v1 * v1 + v2 * v2 + 1e-12f);
    size_t o = (size_t)n * 256 + u;
    f0[(size_t)n * 512 + u] = f2bf(s);
    f0[(size_t)n * 512 + 256 + u] = f2bf(nv);
    xv[o] = f2bf(v0);
    xv[ps + o] = f2bf(v1);
    xv[2 * ps + o] = f2bf(v2);
}

// ---------------- GEMM: C = act(A @ B^T + bias), tile 128x256, BK=64, 8 waves ----------------
// mode 0: A = Ap + zi*az + row*lda (bf16)
// mode 2: A[row][u] = xsrc[(zi%3)*xps + row*256 + u] * gp[(zi/3)*gz + row*gld + 256 + u]
__global__ __launch_bounds__(512)
void gemm_k(const u16* __restrict__ Ap, int lda, long az,
            const u16* __restrict__ xsrc, long xps,
            const u16* __restrict__ gp, int gld, long gz,
            const u16* __restrict__ Bt, long bz,
            const float* __restrict__ bias, int bsz,
            u16* __restrict__ C, int ldc, long czs, long czp,
            int K, int mode, int act, int nshift)
{
    const int tid = threadIdx.x;
    const int lane = tid & 63;
    const int wid = tid >> 6;
    const int wr = wid >> 2, wc = wid & 3;
    const int lr = lane & 15, hk = lane >> 4;

    // bijective XCD-chunked swizzle (col-fastest decode)
    int nwg = gridDim.x;
    int lid = blockIdx.x;
    int wg;
    if ((nwg & 7) == 0) { int q = nwg >> 3; wg = (lid & 7) * q + (lid >> 3); }
    else wg = lid;
    const long row0 = (long)(wg >> nshift) * 128;
    const int n0 = (wg & ((1 << nshift) - 1)) * 256;
    const int zi = blockIdx.y;
    const int side = (mode == 2) ? zi / 3 : zi;
    const int pl = zi % 3;

    const u16* Bz = Bt + (size_t)side * bz;
    long coff = (mode == 2) ? (side * czs + pl * czp) : zi * czs;

    __shared__ __align__(16) u16 Asm[128 * 64];
    __shared__ __align__(16) u16 Bsm[256 * 64];

    f32x4 acc[4][4];
#pragma unroll
    for (int m = 0; m < 4; m++)
#pragma unroll
        for (int n = 0; n < 4; n++) acc[m][n] = (f32x4){0.f, 0.f, 0.f, 0.f};

    for (int kt = 0; kt < K; kt += 64) {
        // ---- stage B tile [256 cols][64 k] ----
#pragma unroll
        for (int it = 0; it < 4; ++it) {
            int idx = it * 512 + tid;
            int r = idx >> 3;
            int c8 = (idx & 7) * 8;
            const u16* g = Bz + (size_t)(n0 + r) * K + kt + c8;
            u16* l = &Bsm[(size_t)(it * 512 + (tid & 0x1C0)) * 8];
            gload_lds16(g, l);
        }
        // ---- stage A tile [128 rows][64 k] ----
        if (mode == 0) {
#pragma unroll
            for (int it = 0; it < 2; ++it) {
                int idx = it * 512 + tid;
                int r = idx >> 3;
                int c8 = (idx & 7) * 8;
                const u16* g = Ap + (size_t)zi * az + (size_t)(row0 + r) * lda + kt + c8;
                u16* l = &Asm[(size_t)(it * 512 + (tid & 0x1C0)) * 8];
                gload_lds16(g, l);
            }
        } else {
#pragma unroll
            for (int it = 0; it < 2; ++it) {
                int idx = it * 512 + tid;
                int r = idx >> 3;
                int c8 = (idx & 7) * 8;
                long row = row0 + r;
                int u = kt + c8;
                union { short8 v; u16 s[8]; } gg, tu, pk;
                gg.v = *(const short8*)(gp + (size_t)side * gz + (size_t)row * gld + 256 + u);
                tu.v = *(const short8*)(xsrc + (size_t)pl * xps + (size_t)row * 256 + u);
#pragma unroll
                for (int j = 0; j < 8; j++) pk.s[j] = f2bf(bf2f(tu.s[j]) * bf2f(gg.s[j]));
                *(short8*)&Asm[(size_t)idx * 8] = pk.v;
            }
        }
        asm volatile("s_waitcnt vmcnt(0)" ::: "memory");
        __syncthreads();

        // ---- compute ----
#pragma unroll
        for (int kk = 0; kk < 2; ++kk) {
            short8 a[4], b[4];
#pragma unroll
            for (int m = 0; m < 4; m++)
                a[m] = *(const short8*)&Asm[(size_t)(wr * 64 + m * 16 + lr) * 64 + kk * 32 + hk * 8];
#pragma unroll
            for (int n = 0; n < 4; n++)
                b[n] = *(const short8*)&Bsm[(size_t)(wc * 64 + n * 16 + lr) * 64 + kk * 32 + hk * 8];
#pragma unroll
            for (int m = 0; m < 4; m++)
#pragma unroll
                for (int n = 0; n < 4; n++)
                    acc[m][n] = __builtin_amdgcn_mfma_f32_16x16x32_bf16(a[m], b[n], acc[m][n], 0, 0, 0);
        }
        __syncthreads();
    }

    // ---- epilogue ----
#pragma unroll
    for (int n = 0; n < 4; n++) {
        int col = n0 + wc * 64 + n * 16 + lr;
        float bv = bias ? bias[(size_t)zi * bsz + col] : 0.0f;
#pragma unroll
        for (int m = 0; m < 4; m++) {
#pragma unroll
            for (int j = 0; j < 4; j++) {
                long row = row0 + wr * 64 + m * 16 + hk * 4 + j;
                float v = acc[m][n][j] + bv;
                if (act) v = v * (1.0f / (1.0f + __expf(-v)));
                C[coff + (size_t)row * ldc + col] = f2bf(v);
            }
        }
    }
}

// ---------------- tensor product + residual -> f0', tv planes ----------------
__global__ void tp_res(const u16* __restrict__ xl, const u16* xr_,
                       const float* __restrict__ tpw, const u16* __restrict__ xv,
                       u16* f0, u16* tv, long ps)
{
    int n = blockIdx.x, u = threadIdx.x;
    size_t o = (size_t)n * 256 + u;
    float s1 = bf2f(xl[o]);
    float a1x = bf2f(xl[ps + o]), a1y = bf2f(xl[2 * ps + o]), a1z = bf2f(xl[3 * ps + o]);
    float s2 = bf2f(xr_[o]);
    float b1x = bf2f(xr_[ps + o]), b1y = bf2f(xr_[2 * ps + o]), b1z = bf2f(xr_[3 * ps + o]);
    float xs = bf2f(f0[(size_t)n * 512 + u]);
    float rx = bf2f(xv[o]), ry = bf2f(xv[ps + o]), rz = bf2f(xv[2 * ps + o]);
    float w0 = tpw[u], w1 = tpw[256 + u], w2 = tpw[512 + u], w3 = tpw[768 + u], w4 = tpw[1024 + u];

    float dot = a1x * b1x + a1y * b1y + a1z * b1z;
    float cx = a1y * b1z - a1z * b1y;
    float cy = a1z * b1x - a1x * b1z;
    float cz = a1x * b1y - a1y * b1x;

    float out0 = A0C * (w0 * s1 * s2 + w3 * INV3C * dot) + xs;
    float ox = A1C * (INV3C * (w1 * s1 * b1x + w2 * s2 * a1x) + INV6C * w4 * cx) + rx;
    float oy = A1C * (INV3C * (w1 * s1 * b1y + w2 * s2 * a1y) + INV6C * w4 * cy) + ry;
    float oz = A1C * (INV3C * (w1 * s1 * b1z + w2 * s2 * a1z) + INV6C * w4 * cz) + rz;

    float nv = sqrtf(ox * ox + oy * oy + oz * oz + 1e-12f);
    f0[(size_t)n * 512 + u] = f2bf(out0);
    f0[(size_t)n * 512 + 256 + u] = f2bf(nv);
    tv[o] = f2bf(ox);
    tv[ps + o] = f2bf(oy);
    tv[2 * ps + o] = f2bf(oz);
}

// ---------------- repack planar -> interleaved + old_fii (LDS transpose) ----------------
__global__ void repack(const u16* __restrict__ outp, const float* __restrict__ old,
                       float* __restrict__ out, long ps)
{
    __shared__ float add[1024];
    int n = blockIdx.x, u = threadIdx.x;
    size_t o = (size_t)n * 256 + u;
    add[u] = bf2f(outp[o]);
    float vx = bf2f(outp[ps + o]);
    float vy = bf2f(outp[2 * ps + o]);
    float vz = bf2f(outp[3 * ps + o]);
    add[256 + 3 * u] = vx;
    add[256 + 3 * u + 1] = vy;
    add[256 + 3 * u + 2] = vz;
    __syncthreads();
    float4 o4 = ((const float4*)(old + (size_t)n * 1024))[u];
    float4 r;
    r.x = o4.x + add[4 * u];
    r.y = o4.y + add[4 * u + 1];
    r.z = o4.z + add[4 * u + 2];
    r.w = o4.w + add[4 * u + 3];
    ((float4*)(out + (size_t)n * 1024))[u] = r;
}

// weight offsets (u16 elements)
enum {
    OFF_ng12w1 = 0,        // 1024x512: ng1_w1 rows 0-511, ng2_w1 rows 512-1023
    OFF_ng1w2  = 524288,   // 512x512
    OFF_ng2w2  = 786432,   // 512x512 (stride 262144 from ng1w2)
    OFF_ngow1  = 1048576,
    OFF_ngow2  = 1310720,
    OFF_l12w0  = 1572864,  // 2 x 256x256 (stride 65536)
    OFF_l12w1  = 1703936,  // 2 x 256x256
    OFF_l3w0   = 1835008,
    OFF_l3w1   = 1900544
};
#define BIAS_BYTE_OFF 3932160
enum { BOFF_mlp1 = 0, BOFF_mlp2 = 1024, BOFF_ngo1 = 2048, BOFF_ngo2 = 2560,
       BOFF_l12 = 3072, BOFF_l3 = 3584 };

extern "C" void kernel_launch(void* const* d_in, const int* in_sizes, int n_in,
                              void* d_out, int out_size, void* d_ws, size_t ws_size,
                              hipStream_t stream) {
    const float* x      = (const float*)d_in[0];
    const float* oldf   = (const float*)d_in[1];
    const float* ng1_w1 = (const float*)d_in[2];
    const float* ng1_b1 = (const float*)d_in[3];
    const float* ng1_w2 = (const float*)d_in[4];
    const float* ng1_b2 = (const float*)d_in[5];
    const float* ng2_w1 = (const float*)d_in[6];
    const float* ng2_b1 = (const float*)d_in[7];
    const float* ng2_w2 = (const float*)d_in[8];
    const float* ng2_b2 = (const float*)d_in[9];
    const float* ngo_w1 = (const float*)d_in[10];
    const float* ngo_b1 = (const float*)d_in[11];
    const float* ngo_w2 = (const float*)d_in[12];
    const float* ngo_b2 = (const float*)d_in[13];
    const float* l1_w0  = (const float*)d_in[14];
    const float* l1_b0  = (const float*)d_in[15];
    const float* l1_w1  = (const float*)d_in[16];
    const float* l2_w0  = (const float*)d_in[17];
    const float* l2_b0  = (const float*)d_in[18];
    const float* l2_w1  = (const float*)d_in[19];
    const float* l3_w0  = (const float*)d_in[20];
    const float* l3_b0  = (const float*)d_in[21];
    const float* l3_w1  = (const float*)d_in[22];
    const float* tpw    = (const float*)d_in[23];

    u16* wts = (u16*)d_ws;
    char* wsb = (char*)d_ws;
    float* biasf = (float*)(wsb + BIAS_BYTE_OFF);

    WArgs wa;
    wa.w[0]  = { ng1_w1, wts + OFF_ng12w1,          512, 1.0f };
    wa.w[1]  = { ng2_w1, wts + OFF_ng12w1 + 262144, 512, 1.0f };
    wa.w[2]  = { ng1_w2, wts + OFF_ng1w2,           512, 1.0f };
    wa.w[3]  = { ng2_w2, wts + OFF_ng2w2,           512, 1.0f };
    wa.w[4]  = { ngo_w1, wts + OFF_ngow1,           512, 1.0f };
    wa.w[5]  = { ngo_w2, wts + OFF_ngow2,           512, 1.0f };
    wa.w[6]  = { l1_w0, wts + OFF_l12w0,            256, 0.0625f };
    wa.w[7]  = { l2_w0, wts + OFF_l12w0 + 65536,    256, 0.0625f };
    wa.w[8]  = { l1_w1, wts + OFF_l12w1,            256, 0.0625f };
    wa.w[9]  = { l2_w1, wts + OFF_l12w1 + 65536,    256, 0.0625f };
    wa.w[10] = { l3_w0, wts + OFF_l3w0,             256, 0.0625f };
    wa.w[11] = { l3_w1, wts + OFF_l3w1,             256, 0.0625f };
    cvt_weights<<<dim3(16, 16, 12), dim3(32, 8), 0, stream>>>(wa);

    BArgs ba;
    ba.b[0] = { ng1_b1, biasf + BOFF_mlp1,       512 };
    ba.b[1] = { ng2_b1, biasf + BOFF_mlp1 + 512, 512 };
    ba.b[2] = { ng1_b2, biasf + BOFF_mlp2,       512 };
    ba.b[3] = { ng2_b2, biasf + BOFF_mlp2 + 512, 512 };
    ba.b[4] = { ngo_b1, biasf + BOFF_ngo1,       512 };
    ba.b[5] = { ngo_b2, biasf + BOFF_ngo2,       512 };
    ba.b[6] = { l1_b0, biasf + BOFF_l12,         256 };
    ba.b[7] = { l2_b0, biasf + BOFF_l12 + 256,   256 };
    ba.b[8] = { l3_b0, biasf + BOFF_l3,          256 };
    pack_bias<<<9, 256, 0, stream>>>(ba);

    long Nn = (long)in_sizes[0] / 1024;

    // chunking so ws fits: peak = 4MiB + Nc*10752 bytes
    int c = 1;
    while (c < 256 && (unsigned long long)(4ULL << 20) + (unsigned long long)(Nn / c) * 10752ULL > (unsigned long long)ws_size)
        c <<= 1;
    long Nc = Nn / c;

    u16* F0 = (u16*)(wsb + (4 << 20));       // [Nc,512]
    u16* H  = F0 + (size_t)Nc * 512;         // [Nc,1024] (fused)
    u16* G  = H + (size_t)Nc * 1024;         // [Nc,1024] (fused gates)
    u16* XV = G + (size_t)Nc * 1024;         // [3][Nc,256]
    u16* XL = XV + (size_t)Nc * 768;         // [4][Nc,256]
    // XR = XL + 4*ps (contiguous, czs = 4*ps)
    long ps = Nc * 256;
    u16* XR = XL + 4 * ps;
    u16* TV = XR + ps;                       // aliases XR vector planes
    u16* OUTP = XL;                          // aliases XL (dead after tp_res)

    dim3 blk(512);
    int mt = (int)(Nc / 128);

    for (int ch = 0; ch < c; ++ch) {
        const float* xk  = x + (size_t)ch * Nc * 1024;
        const float* ok  = oldf + (size_t)ch * Nc * 1024;
        float* outk = (float*)d_out + (size_t)ch * Nc * 1024;

        prep_f0<<<(int)Nc, 256, 0, stream>>>(xk, F0, XV, ps);

        // MLP1 fused (ng1|ng2): H[N,1024] = silu(F0 @ W^T + b)
        gemm_k<<<dim3(mt * 4, 1), blk, 0, stream>>>(F0, 512, 0, nullptr, 0, nullptr, 0, 0,
            wts + OFF_ng12w1, 0, biasf + BOFF_mlp1, 0, H, 1024, 0, 0, 512, 0, 1, 2);
        // MLP2 z-batched: G[:, z*512:] = H[:, z*512:] @ w2_z^T + b
        gemm_k<<<dim3(mt * 2, 2), blk, 0, stream>>>(H, 1024, 512, nullptr, 0, nullptr, 0, 0,
            wts + OFF_ng1w2, 262144, biasf + BOFF_mlp2, 512, G, 1024, 512, 0, 512, 0, 0, 1);
        // scalar linears z=2: XL/XR plane0 = G[:, z*512:z*512+256] @ l_w0^T + b0
        gemm_k<<<dim3(mt, 2), blk, 0, stream>>>(G, 1024, 512, nullptr, 0, nullptr, 0, 0,
            wts + OFF_l12w0, 65536, biasf + BOFF_l12, 256, XL, 256, 4 * ps, 0, 256, 0, 0, 0);
        // gated vector linears z=6 (side=z/3, plane=z%3)
        gemm_k<<<dim3(mt, 6), blk, 0, stream>>>(nullptr, 0, 0, XV, ps, G, 1024, 512,
            wts + OFF_l12w1, 65536, nullptr, 0, XL + ps, 256, 4 * ps, ps, 256, 2, 0, 0);

        // tensor product + residual -> F0', TV
        tp_res<<<(int)Nc, 256, 0, stream>>>(XL, XR, tpw, XV, F0, TV, ps);

        // ngo MLP (N=512), H/G reused as [Nc,512] packed
        gemm_k<<<dim3(mt * 2, 1), blk, 0, stream>>>(F0, 512, 0, nullptr, 0, nullptr, 0, 0,
            wts + OFF_ngow1, 0, biasf + BOFF_ngo1, 0, H, 512, 0, 0, 512, 0, 1, 1);
        gemm_k<<<dim3(mt * 2, 1), blk, 0, stream>>>(H, 512, 0, nullptr, 0, nullptr, 0, 0,
            wts + OFF_ngow2, 0, biasf + BOFF_ngo2, 0, G, 512, 0, 0, 512, 0, 0, 1);
        // lin3 scalar
        gemm_k<<<dim3(mt, 1), blk, 0, stream>>>(G, 512, 0, nullptr, 0, nullptr, 0, 0,
            wts + OFF_l3w0, 0, biasf + BOFF_l3, 0, OUTP, 256, 0, 0, 256, 0, 0, 0);
        // lin3 gated vector z=3 (side=0)
        gemm_k<<<dim3(mt, 3), blk, 0, stream>>>(nullptr, 0, 0, TV, ps, G, 512, 0,
            wts + OFF_l3w1, 0, nullptr, 0, OUTP + ps, 256, 0, ps, 256, 2, 0, 0);

        // repack + old_fii -> out
        repack<<<(int)Nc, 256, 0, stream>>>(OUTP, ok, outk, ps);
    }
}

// Round 4
// 593.552 us; speedup vs baseline: 1.3352x; 1.0519x over previous
//
#include <hip/hip_runtime.h>
#include <stdint.h>
#include <math.h>

typedef unsigned short u16;
typedef __attribute__((ext_vector_type(8))) short short8;
typedef __attribute__((ext_vector_type(4))) float f32x4;

#define A0C 0.44721359549995793f
#define A1C 0.77459666924148340f
#define INV3C 0.57735026918962584f
#define INV6C 0.40824829046386302f

__device__ __forceinline__ float bf2f(u16 u) {
    unsigned v = ((unsigned)u) << 16; float f; __builtin_memcpy(&f, &v, 4); return f;
}
__device__ __forceinline__ u16 f2bf(float f) {
    unsigned u; __builtin_memcpy(&u, &f, 4);
    u += 0x7fffu + ((u >> 16) & 1u);
    return (u16)(u >> 16);
}

__device__ __forceinline__ void gload_lds16(const void* g, void* l) {
    __builtin_amdgcn_global_load_lds((const __attribute__((address_space(1))) unsigned*)g,
                                     (__attribute__((address_space(3))) unsigned*)l, 16, 0, 0);
}

// ---------------- weight transpose + bf16 convert ----------------
struct WDesc { const float* s; u16* d; int n; float sc; };
struct WArgs { WDesc w[12]; };

__global__ void cvt_weights(WArgs args) {
    WDesc wd = args.w[blockIdx.z];
    int n = wd.n;
    int x0 = blockIdx.x * 32, y0 = blockIdx.y * 32;
    if (x0 >= n || y0 >= n) return;
    __shared__ float tile[32][33];
    int tx = threadIdx.x, ty = threadIdx.y;
#pragma unroll
    for (int j = 0; j < 4; j++)
        tile[ty + 8 * j][tx] = wd.s[(size_t)(y0 + ty + 8 * j) * n + x0 + tx];
    __syncthreads();
#pragma unroll
    for (int j = 0; j < 4; j++)
        wd.d[(size_t)(x0 + ty + 8 * j) * n + y0 + tx] = f2bf(tile[tx][ty + 8 * j] * wd.sc);
}

// ---------------- bias pack ----------------
struct BDesc { const float* s; float* d; int n; };
struct BArgs { BDesc b[9]; };
__global__ void pack_bias(BArgs a) {
    BDesc b = a.b[blockIdx.x];
    for (int i = threadIdx.x; i < b.n; i += 256) b.d[i] = b.s[i];
}

// ---------------- prep: f0 = [s,|v|] bf16, XV planar bf16 ----------------
__global__ void prep_f0(const float* __restrict__ x, u16* __restrict__ f0,
                        u16* __restrict__ xv, long ps) {
    __shared__ float row[1024];
    int n = blockIdx.x, u = threadIdx.x;
    const float4* xr = (const float4*)(x + (size_t)n * 1024);
    float4 v4 = xr[u];
    row[4 * u] = v4.x; row[4 * u + 1] = v4.y; row[4 * u + 2] = v4.z; row[4 * u + 3] = v4.w;
    __syncthreads();
    float s = row[u];
    float v0 = row[256 + 3 * u], v1 = row[256 + 3 * u + 1], v2 = row[256 + 3 * u + 2];
    float nv = sqrtf(v0 * v0 + v1 * v1 + v2 * v2 + 1e-12f);
    size_t o = (size_t)n * 256 + u;
    f0[(size_t)n * 512 + u] = f2bf(s);
    f0[(size_t)n * 512 + 256 + u] = f2bf(nv);
    xv[o] = f2bf(v0);
    xv[ps + o] = f2bf(v1);
    xv[2 * ps + o] = f2bf(v2);
}

// ---------------- GEMM 256x256 tile, BK=64, dbuf LDS, T2 swizzle ----------------
// mode 0: A = Ap + zi*az + row*lda
// mode 2: A-rows are plane-stacked (M=3*nc): plane p = row/nc, in-plane rr = row%nc;
//         A[row][u] = xsrc[row*256+u] * gp[zi*gz + rr*gld + 256+u]
// C: mode0 at C + zi*czs + row*ldc; mode2 at C + zi*czs + p*czp + rr*ldc
__global__ __launch_bounds__(512, 2)
void gemm256(const u16* __restrict__ Ap, int lda, long az,
             const u16* __restrict__ xsrc,
             const u16* __restrict__ gp, int gld, long gz,
             const u16* __restrict__ Bt, long bz,
             const float* __restrict__ bias, int bsz,
             u16* __restrict__ C, int ldc, long czs, long czp,
             int K, long nc, int mode, int act, int nshift)
{
    extern __shared__ __align__(16) u16 sm[];   // 2 x (A 256*64 + B 256*64) = 128 KiB
    u16* As = sm;            // [buf][256*64] : buf*16384
    u16* Bs = sm + 32768;

    const int tid = threadIdx.x;
    const int lane = tid & 63;
    const int wid = tid >> 6;
    const int wr = wid >> 2, wc = wid & 3;
    const int lr = lane & 15, hk = lane >> 4;

    // bijective XCD-chunked swizzle
    int nwg = gridDim.x;
    int lid = blockIdx.x;
    int wg;
    if ((nwg & 7) == 0) { int q = nwg >> 3; wg = (lid & 7) * q + (lid >> 3); }
    else wg = lid;
    const long row0 = (long)(wg >> nshift) * 256;
    const int n0 = (wg & ((1 << nshift) - 1)) * 256;
    const int zi = blockIdx.y;

    long p = 0, rr0 = row0;
    if (mode == 2) { p = row0 / nc; rr0 = row0 - p * nc; }

    const u16* Bz = Bt + (size_t)zi * bz;
    const long cbase = (mode == 2) ? (zi * czs + p * czp + rr0 * ldc)
                                   : (zi * czs + row0 * ldc);

    f32x4 acc[8][4];
#pragma unroll
    for (int m = 0; m < 8; m++)
#pragma unroll
        for (int n = 0; n < 4; n++) acc[m][n] = (f32x4){0.f, 0.f, 0.f, 0.f};

    auto stageB = [&](int buf, int kt) {
#pragma unroll
        for (int it = 0; it < 4; ++it) {
            int idx = it * 512 + tid;
            int r = idx >> 3, s = idx & 7;
            const u16* g = Bz + (size_t)(n0 + r) * K + kt + ((s ^ (r & 7)) * 8);
            u16* l = Bs + buf * 16384 + (size_t)(it * 512 + (tid & 0x1C0)) * 8;
            gload_lds16(g, l);
        }
    };
    auto stageA0 = [&](int buf, int kt) {
#pragma unroll
        for (int it = 0; it < 4; ++it) {
            int idx = it * 512 + tid;
            int r = idx >> 3, s = idx & 7;
            const u16* g = Ap + (size_t)zi * az + (row0 + r) * (size_t)lda + kt + ((s ^ (r & 7)) * 8);
            u16* l = As + buf * 16384 + (size_t)(it * 512 + (tid & 0x1C0)) * 8;
            gload_lds16(g, l);
        }
    };
    auto stageA2 = [&](int buf, int kt) {
#pragma unroll
        for (int it = 0; it < 4; ++it) {
            int idx = it * 512 + tid;
            int r = idx >> 3, s = idx & 7;
            int u = kt + s * 8;
            union { short8 v; u16 h[8]; } gg, tu, pk;
            gg.v = *(const short8*)(gp + (size_t)zi * gz + (rr0 + r) * (size_t)gld + 256 + u);
            tu.v = *(const short8*)(xsrc + (row0 + r) * 256 + u);
#pragma unroll
            for (int j = 0; j < 8; j++) pk.h[j] = f2bf(bf2f(tu.h[j]) * bf2f(gg.h[j]));
            *(short8*)&As[buf * 16384 + ((size_t)r * 8 + (s ^ (r & 7))) * 8] = pk.v;
        }
    };

    const int nt = K >> 6;
    // prologue: stage tile 0
    stageB(0, 0);
    if (mode == 0) stageA0(0, 0); else stageA2(0, 0);
    __syncthreads();

    int buf = 0;
    for (int t = 0; t < nt; ++t) {
        // issue next tile's stage BEFORE compute (latency hides under MFMA)
        if (t + 1 < nt) {
            int kt = (t + 1) << 6;
            stageB(buf ^ 1, kt);
            if (mode == 0) stageA0(buf ^ 1, kt); else stageA2(buf ^ 1, kt);
        }
        const int ao = buf * 16384, bo = buf * 16384;
#pragma unroll
        for (int kk = 0; kk < 2; ++kk) {
            short8 b[4];
#pragma unroll
            for (int n = 0; n < 4; n++) {
                int cb = wc * 64 + n * 16 + lr;
                int sl = (kk * 4 + hk) ^ (cb & 7);
                b[n] = *(const short8*)&Bs[bo + (size_t)cb * 64 + sl * 8];
            }
#pragma unroll
            for (int m = 0; m < 8; m++) {
                int ra = wr * 128 + m * 16 + lr;
                int sl = (kk * 4 + hk) ^ (ra & 7);
                short8 a = *(const short8*)&As[ao + (size_t)ra * 64 + sl * 8];
#pragma unroll
                for (int n = 0; n < 4; n++)
                    acc[m][n] = __builtin_amdgcn_mfma_f32_16x16x32_bf16(a, b[n], acc[m][n], 0, 0, 0);
            }
        }
        __syncthreads();   // drains vmcnt+lgkm: next buf staged, this buf free
        buf ^= 1;
    }

    // ---- epilogue ----
#pragma unroll
    for (int n = 0; n < 4; n++) {
        int col = n0 + wc * 64 + n * 16 + lr;
        float bv = (bias && mode == 0) ? bias[(size_t)zi * bsz + col] : 0.0f;
#pragma unroll
        for (int m = 0; m < 8; m++) {
#pragma unroll
            for (int j = 0; j < 4; j++) {
                long rit = wr * 128 + m * 16 + hk * 4 + j;
                float v = acc[m][n][j] + bv;
                if (act) v = v * (1.0f / (1.0f + __expf(-v)));
                C[cbase + rit * (size_t)ldc + col] = f2bf(v);
            }
        }
    }
}

// ---------------- tensor product + residual -> f0', tv planes ----------------
__global__ void tp_res(const u16* __restrict__ xl, const u16* xr_,
                       const float* __restrict__ tpw, const u16* __restrict__ xv,
                       u16* f0, u16* tv, long ps)
{
    int n = blockIdx.x, u = threadIdx.x;
    size_t o = (size_t)n * 256 + u;
    float s1 = bf2f(xl[o]);
    float a1x = bf2f(xl[ps + o]), a1y = bf2f(xl[2 * ps + o]), a1z = bf2f(xl[3 * ps + o]);
    float s2 = bf2f(xr_[o]);
    float b1x = bf2f(xr_[ps + o]), b1y = bf2f(xr_[2 * ps + o]), b1z = bf2f(xr_[3 * ps + o]);
    float xs = bf2f(f0[(size_t)n * 512 + u]);
    float rx = bf2f(xv[o]), ry = bf2f(xv[ps + o]), rz = bf2f(xv[2 * ps + o]);
    float w0 = tpw[u], w1 = tpw[256 + u], w2 = tpw[512 + u], w3 = tpw[768 + u], w4 = tpw[1024 + u];

    float dot = a1x * b1x + a1y * b1y + a1z * b1z;
    float cx = a1y * b1z - a1z * b1y;
    float cy = a1z * b1x - a1x * b1z;
    float cz = a1x * b1y - a1y * b1x;

    float out0 = A0C * (w0 * s1 * s2 + w3 * INV3C * dot) + xs;
    float ox = A1C * (INV3C * (w1 * s1 * b1x + w2 * s2 * a1x) + INV6C * w4 * cx) + rx;
    float oy = A1C * (INV3C * (w1 * s1 * b1y + w2 * s2 * a1y) + INV6C * w4 * cy) + ry;
    float oz = A1C * (INV3C * (w1 * s1 * b1z + w2 * s2 * a1z) + INV6C * w4 * cz) + rz;

    float nv = sqrtf(ox * ox + oy * oy + oz * oz + 1e-12f);
    f0[(size_t)n * 512 + u] = f2bf(out0);
    f0[(size_t)n * 512 + 256 + u] = f2bf(nv);
    tv[o] = f2bf(ox);
    tv[ps + o] = f2bf(oy);
    tv[2 * ps + o] = f2bf(oz);
}

// ---------------- repack planar -> interleaved + old_fii (LDS transpose) ----------------
__global__ void repack(const u16* __restrict__ outp, const float* __restrict__ old,
                       float* __restrict__ out, long ps)
{
    __shared__ float add[1024];
    int n = blockIdx.x, u = threadIdx.x;
    size_t o = (size_t)n * 256 + u;
    add[u] = bf2f(outp[o]);
    float vx = bf2f(outp[ps + o]);
    float vy = bf2f(outp[2 * ps + o]);
    float vz = bf2f(outp[3 * ps + o]);
    add[256 + 3 * u] = vx;
    add[256 + 3 * u + 1] = vy;
    add[256 + 3 * u + 2] = vz;
    __syncthreads();
    float4 o4 = ((const float4*)(old + (size_t)n * 1024))[u];
    float4 r;
    r.x = o4.x + add[4 * u];
    r.y = o4.y + add[4 * u + 1];
    r.z = o4.z + add[4 * u + 2];
    r.w = o4.w + add[4 * u + 3];
    ((float4*)(out + (size_t)n * 1024))[u] = r;
}

// weight offsets (u16 elements)
enum {
    OFF_ng12w1 = 0,        // 1024x512
    OFF_ng1w2  = 524288,   // 2 x 512x512 (stride 262144)
    OFF_ngow1  = 1048576,
    OFF_ngow2  = 1310720,
    OFF_l12w0  = 1572864,  // 2 x 256x256 (stride 65536)
    OFF_l12w1  = 1703936,
    OFF_l3w0   = 1835008,
    OFF_l3w1   = 1900544
};
#define BIAS_BYTE_OFF 3932160
enum { BOFF_mlp1 = 0, BOFF_mlp2 = 1024, BOFF_ngo1 = 2048, BOFF_ngo2 = 2560,
       BOFF_l12 = 3072, BOFF_l3 = 3584 };

extern "C" void kernel_launch(void* const* d_in, const int* in_sizes, int n_in,
                              void* d_out, int out_size, void* d_ws, size_t ws_size,
                              hipStream_t stream) {
    const float* x      = (const float*)d_in[0];
    const float* oldf   = (const float*)d_in[1];
    const float* ng1_w1 = (const float*)d_in[2];
    const float* ng1_b1 = (const float*)d_in[3];
    const float* ng1_w2 = (const float*)d_in[4];
    const float* ng1_b2 = (const float*)d_in[5];
    const float* ng2_w1 = (const float*)d_in[6];
    const float* ng2_b1 = (const float*)d_in[7];
    const float* ng2_w2 = (const float*)d_in[8];
    const float* ng2_b2 = (const float*)d_in[9];
    const float* ngo_w1 = (const float*)d_in[10];
    const float* ngo_b1 = (const float*)d_in[11];
    const float* ngo_w2 = (const float*)d_in[12];
    const float* ngo_b2 = (const float*)d_in[13];
    const float* l1_w0  = (const float*)d_in[14];
    const float* l1_b0  = (const float*)d_in[15];
    const float* l1_w1  = (const float*)d_in[16];
    const float* l2_w0  = (const float*)d_in[17];
    const float* l2_b0  = (const float*)d_in[18];
    const float* l2_w1  = (const float*)d_in[19];
    const float* l3_w0  = (const float*)d_in[20];
    const float* l3_b0  = (const float*)d_in[21];
    const float* l3_w1  = (const float*)d_in[22];
    const float* tpw    = (const float*)d_in[23];

    u16* wts = (u16*)d_ws;
    char* wsb = (char*)d_ws;
    float* biasf = (float*)(wsb + BIAS_BYTE_OFF);

    WArgs wa;
    wa.w[0]  = { ng1_w1, wts + OFF_ng12w1,          512, 1.0f };
    wa.w[1]  = { ng2_w1, wts + OFF_ng12w1 + 262144, 512, 1.0f };
    wa.w[2]  = { ng1_w2, wts + OFF_ng1w2,           512, 1.0f };
    wa.w[3]  = { ng2_w2, wts + OFF_ng1w2 + 262144,  512, 1.0f };
    wa.w[4]  = { ngo_w1, wts + OFF_ngow1,           512, 1.0f };
    wa.w[5]  = { ngo_w2, wts + OFF_ngow2,           512, 1.0f };
    wa.w[6]  = { l1_w0, wts + OFF_l12w0,            256, 0.0625f };
    wa.w[7]  = { l2_w0, wts + OFF_l12w0 + 65536,    256, 0.0625f };
    wa.w[8]  = { l1_w1, wts + OFF_l12w1,            256, 0.0625f };
    wa.w[9]  = { l2_w1, wts + OFF_l12w1 + 65536,    256, 0.0625f };
    wa.w[10] = { l3_w0, wts + OFF_l3w0,             256, 0.0625f };
    wa.w[11] = { l3_w1, wts + OFF_l3w1,             256, 0.0625f };
    cvt_weights<<<dim3(16, 16, 12), dim3(32, 8), 0, stream>>>(wa);

    BArgs ba;
    ba.b[0] = { ng1_b1, biasf + BOFF_mlp1,       512 };
    ba.b[1] = { ng2_b1, biasf + BOFF_mlp1 + 512, 512 };
    ba.b[2] = { ng1_b2, biasf + BOFF_mlp2,       512 };
    ba.b[3] = { ng2_b2, biasf + BOFF_mlp2 + 512, 512 };
    ba.b[4] = { ngo_b1, biasf + BOFF_ngo1,       512 };
    ba.b[5] = { ngo_b2, biasf + BOFF_ngo2,       512 };
    ba.b[6] = { l1_b0, biasf + BOFF_l12,         256 };
    ba.b[7] = { l2_b0, biasf + BOFF_l12 + 256,   256 };
    ba.b[8] = { l3_b0, biasf + BOFF_l3,          256 };
    pack_bias<<<9, 256, 0, stream>>>(ba);

    long Nn = (long)in_sizes[0] / 1024;

    // chunking: ws fit AND Nc <= 16384 (chunk intermediates L3-resident)
    int c = 1;
    while (c < 256 &&
           ((unsigned long long)(4ULL << 20) + (unsigned long long)(Nn / c) * 10752ULL > (unsigned long long)ws_size
            || (Nn / c) > 16384))
        c <<= 1;
    long Nc = Nn / c;

    u16* F0 = (u16*)(wsb + (4 << 20));       // [Nc,512]
    u16* H  = F0 + (size_t)Nc * 512;         // [Nc,1024]
    u16* G  = H + (size_t)Nc * 1024;         // [Nc,1024]
    u16* XV = G + (size_t)Nc * 1024;         // [3][Nc,256]
    u16* XL = XV + (size_t)Nc * 768;         // [2 sides][4 planes][Nc,256]
    long ps = Nc * 256;
    u16* XR = XL + 4 * ps;
    u16* TV = XR + ps;                       // aliases XR vector planes
    u16* OUTP = XL;                          // aliases XL (dead after tp_res)

    dim3 blk(512);
    const size_t SMEM = 131072;
    int mt = (int)(Nc / 256);

    for (int ch = 0; ch < c; ++ch) {
        const float* xk  = x + (size_t)ch * Nc * 1024;
        const float* ok  = oldf + (size_t)ch * Nc * 1024;
        float* outk = (float*)d_out + (size_t)ch * Nc * 1024;

        prep_f0<<<(int)Nc, 256, 0, stream>>>(xk, F0, XV, ps);

        // MLP1 fused (ng1|ng2): H[Nc,1024] = silu(F0 @ W^T + b)
        gemm256<<<dim3(mt * 4, 1), blk, SMEM, stream>>>(F0, 512, 0, nullptr, nullptr, 0, 0,
            wts + OFF_ng12w1, 0, biasf + BOFF_mlp1, 0, H, 1024, 0, 0, 512, Nc, 0, 1, 2);
        // MLP2 z-batched: G[:, z*512:] = H[:, z*512:] @ w2_z^T + b
        gemm256<<<dim3(mt * 2, 2), blk, SMEM, stream>>>(H, 1024, 512, nullptr, nullptr, 0, 0,
            wts + OFF_ng1w2, 262144, biasf + BOFF_mlp2, 512, G, 1024, 512, 0, 512, Nc, 0, 0, 1);
        // scalar linears z=2
        gemm256<<<dim3(mt, 2), blk, SMEM, stream>>>(G, 1024, 512, nullptr, nullptr, 0, 0,
            wts + OFF_l12w0, 65536, biasf + BOFF_l12, 256, XL, 256, 4 * ps, 0, 256, Nc, 0, 0, 0);
        // gated vector linears: z=2 sides, M=3*Nc plane-stacked
        gemm256<<<dim3(mt * 3, 2), blk, SMEM, stream>>>(nullptr, 0, 0, XV, G, 1024, 512,
            wts + OFF_l12w1, 65536, nullptr, 0, XL + ps, 256, 4 * ps, ps, 256, Nc, 2, 0, 0);

        // tensor product + residual -> F0', TV
        tp_res<<<(int)Nc, 256, 0, stream>>>(XL, XR, tpw, XV, F0, TV, ps);

        // ngo MLP (N=512)
        gemm256<<<dim3(mt * 2, 1), blk, SMEM, stream>>>(F0, 512, 0, nullptr, nullptr, 0, 0,
            wts + OFF_ngow1, 0, biasf + BOFF_ngo1, 0, H, 512, 0, 0, 512, Nc, 0, 1, 1);
        gemm256<<<dim3(mt * 2, 1), blk, SMEM, stream>>>(H, 512, 0, nullptr, nullptr, 0, 0,
            wts + OFF_ngow2, 0, biasf + BOFF_ngo2, 0, G, 512, 0, 0, 512, Nc, 0, 0, 1);
        // lin3 scalar
        gemm256<<<dim3(mt, 1), blk, SMEM, stream>>>(G, 512, 0, nullptr, nullptr, 0, 0,
            wts + OFF_l3w0, 0, biasf + BOFF_l3, 0, OUTP, 256, 0, 0, 256, Nc, 0, 0, 0);
        // lin3 gated: z=1, M=3*Nc from TV
        gemm256<<<dim3(mt * 3, 1), blk, SMEM, stream>>>(nullptr, 0, 0, TV, G, 512, 0,
            wts + OFF_l3w1, 0, nullptr, 0, OUTP + ps, 256, 0, ps, 256, Nc, 2, 0, 0);

        // repack + old_fii -> out
        repack<<<(int)Nc, 256, 0, stream>>>(OUTP, ok, outk, ps);
    }
}

// Round 5
// 539.208 us; speedup vs baseline: 1.4698x; 1.1008x over previous
//
#include <hip/hip_runtime.h>
#include <stdint.h>
#include <math.h>

typedef unsigned short u16;
typedef __attribute__((ext_vector_type(8))) short short8;
typedef __attribute__((ext_vector_type(4))) float f32x4;

#define A0C 0.44721359549995793f
#define A1C 0.77459666924148340f
#define INV3C 0.57735026918962584f
#define INV6C 0.40824829046386302f

__device__ __forceinline__ float bf2f(u16 u) {
    unsigned v = ((unsigned)u) << 16; float f; __builtin_memcpy(&f, &v, 4); return f;
}
__device__ __forceinline__ u16 f2bf(float f) {
    unsigned u; __builtin_memcpy(&u, &f, 4);
    u += 0x7fffu + ((u >> 16) & 1u);
    return (u16)(u >> 16);
}

__device__ __forceinline__ void gload_lds16(const void* g, void* l) {
    __builtin_amdgcn_global_load_lds((const __attribute__((address_space(1))) unsigned*)g,
                                     (__attribute__((address_space(3))) unsigned*)l, 16, 0, 0);
}

// ---------------- weight transpose + bf16 convert ----------------
struct WDesc { const float* s; u16* d; int n; float sc; };
struct WArgs { WDesc w[12]; };

__global__ void cvt_weights(WArgs args) {
    WDesc wd = args.w[blockIdx.z];
    int n = wd.n;
    int x0 = blockIdx.x * 32, y0 = blockIdx.y * 32;
    if (x0 >= n || y0 >= n) return;
    __shared__ float tile[32][33];
    int tx = threadIdx.x, ty = threadIdx.y;
#pragma unroll
    for (int j = 0; j < 4; j++)
        tile[ty + 8 * j][tx] = wd.s[(size_t)(y0 + ty + 8 * j) * n + x0 + tx];
    __syncthreads();
#pragma unroll
    for (int j = 0; j < 4; j++)
        wd.d[(size_t)(x0 + ty + 8 * j) * n + y0 + tx] = f2bf(tile[tx][ty + 8 * j] * wd.sc);
}

// ---------------- bias pack ----------------
struct BDesc { const float* s; float* d; int n; };
struct BArgs { BDesc b[9]; };
__global__ void pack_bias(BArgs a) {
    BDesc b = a.b[blockIdx.x];
    for (int i = threadIdx.x; i < b.n; i += 256) b.d[i] = b.s[i];
}

// ---------------- prep: f0 = [s,|v|] bf16, XV planar bf16 ----------------
__global__ void prep_f0(const float* __restrict__ x, u16* __restrict__ f0,
                        u16* __restrict__ xv, long ps) {
    __shared__ float row[1024];
    int n = blockIdx.x, u = threadIdx.x;
    const float4* xr = (const float4*)(x + (size_t)n * 1024);
    float4 v4 = xr[u];
    row[4 * u] = v4.x; row[4 * u + 1] = v4.y; row[4 * u + 2] = v4.z; row[4 * u + 3] = v4.w;
    __syncthreads();
    float s = row[u];
    float v0 = row[256 + 3 * u], v1 = row[256 + 3 * u + 1], v2 = row[256 + 3 * u + 2];
    float nv = sqrtf(v0 * v0 + v1 * v1 + v2 * v2 + 1e-12f);
    size_t o = (size_t)n * 256 + u;
    f0[(size_t)n * 512 + u] = f2bf(s);
    f0[(size_t)n * 512 + 256 + u] = f2bf(nv);
    xv[o] = f2bf(v0);
    xv[ps + o] = f2bf(v1);
    xv[2 * ps + o] = f2bf(v2);
}

// ---------------- GEMM 256x256 tile, BK=64, dbuf LDS, T2 swizzle ----------------
// mode 0: A = Ap + zi*az + row*lda (bf16), C = C + zi*czs + row*ldc
// mode 2 (merged irrep-linear): rows plane-stacked, M = 4*nc; plane p = row/nc:
//   p==0: A = Ap + zi*az + rr*lda (scalar block of G), B = Bt + zi*bz, bias on
//   p>=1: A[rr][u] = xsrc[(row-nc)*256+u] * gp[zi*gz + rr*gld + 256+u],
//         B = Bt + zi*bz + bw, no bias
//   C = C + zi*czs + p*czp + rr*ldc
__global__ __launch_bounds__(512, 2)
void gemm256(const u16* __restrict__ Ap, int lda, long az,
             const u16* __restrict__ xsrc,
             const u16* __restrict__ gp, int gld, long gz,
             const u16* __restrict__ Bt, long bz, long bw,
             const float* __restrict__ bias, int bsz,
             u16* __restrict__ C, int ldc, long czs, long czp,
             int K, long nc, int mode, int act, int nshift)
{
    extern __shared__ __align__(16) u16 sm[];   // 2 x (A 256*64 + B 256*64) = 128 KiB
    u16* As = sm;
    u16* Bs = sm + 32768;

    const int tid = threadIdx.x;
    const int lane = tid & 63;
    const int wid = tid >> 6;
    const int wr = wid >> 2, wc = wid & 3;
    const int lr = lane & 15, hk = lane >> 4;

    // bijective XCD-chunked swizzle
    int nwg = gridDim.x;
    int lid = blockIdx.x;
    int wg;
    if ((nwg & 7) == 0) { int q = nwg >> 3; wg = (lid & 7) * q + (lid >> 3); }
    else wg = lid;
    const long row0 = (long)(wg >> nshift) * 256;
    const int n0 = (wg & ((1 << nshift) - 1)) * 256;
    const int zi = blockIdx.y;

    long p = 0, rr0 = row0;
    if (mode == 2) { p = row0 / nc; rr0 = row0 - p * nc; }

    const u16* Bz = Bt + (size_t)zi * bz + ((mode == 2 && p > 0) ? bw : 0);
    const long cbase = (mode == 2) ? (zi * czs + p * czp + rr0 * ldc)
                                   : (zi * czs + row0 * ldc);

    f32x4 acc[8][4];
#pragma unroll
    for (int m = 0; m < 8; m++)
#pragma unroll
        for (int n = 0; n < 4; n++) acc[m][n] = (f32x4){0.f, 0.f, 0.f, 0.f};

    auto stageB = [&](int buf, int kt) {
#pragma unroll
        for (int it = 0; it < 4; ++it) {
            int idx = it * 512 + tid;
            int r = idx >> 3, s = idx & 7;
            const u16* g = Bz + (size_t)(n0 + r) * K + kt + ((s ^ (r & 7)) * 8);
            u16* l = Bs + buf * 16384 + (size_t)(it * 512 + (tid & 0x1C0)) * 8;
            gload_lds16(g, l);
        }
    };
    auto stageA0 = [&](int buf, int kt) {
#pragma unroll
        for (int it = 0; it < 4; ++it) {
            int idx = it * 512 + tid;
            int r = idx >> 3, s = idx & 7;
            const u16* g = Ap + (size_t)zi * az + (rr0 + r) * (size_t)lda + kt + ((s ^ (r & 7)) * 8);
            u16* l = As + buf * 16384 + (size_t)(it * 512 + (tid & 0x1C0)) * 8;
            gload_lds16(g, l);
        }
    };
    auto stageA2 = [&](int buf, int kt) {
#pragma unroll
        for (int it = 0; it < 4; ++it) {
            int idx = it * 512 + tid;
            int r = idx >> 3, s = idx & 7;
            int u = kt + s * 8;
            union { short8 v; u16 h[8]; } gg, tu, pk;
            gg.v = *(const short8*)(gp + (size_t)zi * gz + (rr0 + r) * (size_t)gld + 256 + u);
            tu.v = *(const short8*)(xsrc + (size_t)(row0 - nc + r) * 256 + u);
#pragma unroll
            for (int j = 0; j < 8; j++) pk.h[j] = f2bf(bf2f(tu.h[j]) * bf2f(gg.h[j]));
            *(short8*)&As[buf * 16384 + ((size_t)r * 8 + (s ^ (r & 7))) * 8] = pk.v;
        }
    };

    const bool a_direct = (mode == 0) || (p == 0);
    const int nt = K >> 6;
    stageB(0, 0);
    if (a_direct) stageA0(0, 0); else stageA2(0, 0);
    __syncthreads();

    int buf = 0;
    for (int t = 0; t < nt; ++t) {
        if (t + 1 < nt) {
            int kt = (t + 1) << 6;
            stageB(buf ^ 1, kt);
            if (a_direct) stageA0(buf ^ 1, kt); else stageA2(buf ^ 1, kt);
        }
        const int ao = buf * 16384, bo = buf * 16384;
#pragma unroll
        for (int kk = 0; kk < 2; ++kk) {
            short8 b[4];
#pragma unroll
            for (int n = 0; n < 4; n++) {
                int cb = wc * 64 + n * 16 + lr;
                int sl = (kk * 4 + hk) ^ (cb & 7);
                b[n] = *(const short8*)&Bs[bo + (size_t)cb * 64 + sl * 8];
            }
#pragma unroll
            for (int m = 0; m < 8; m++) {
                int ra = wr * 128 + m * 16 + lr;
                int sl = (kk * 4 + hk) ^ (ra & 7);
                short8 a = *(const short8*)&As[ao + (size_t)ra * 64 + sl * 8];
#pragma unroll
                for (int n = 0; n < 4; n++)
                    acc[m][n] = __builtin_amdgcn_mfma_f32_16x16x32_bf16(a, b[n], acc[m][n], 0, 0, 0);
            }
        }
        __syncthreads();
        buf ^= 1;
    }

    // ---- epilogue ----
    const bool use_bias = bias && (mode == 0 || p == 0);
#pragma unroll
    for (int n = 0; n < 4; n++) {
        int col = n0 + wc * 64 + n * 16 + lr;
        float bv = use_bias ? bias[(size_t)zi * bsz + col] : 0.0f;
#pragma unroll
        for (int m = 0; m < 8; m++) {
#pragma unroll
            for (int j = 0; j < 4; j++) {
                long rit = wr * 128 + m * 16 + hk * 4 + j;
                float v = acc[m][n][j] + bv;
                if (act) v = v * (1.0f / (1.0f + __expf(-v)));
                C[cbase + rit * (size_t)ldc + col] = f2bf(v);
            }
        }
    }
}

// ---------------- tensor product + residual -> f0', tv planes ----------------
__global__ void tp_res(const u16* __restrict__ xl, const u16* xr_,
                       const float* __restrict__ tpw, const u16* __restrict__ xv,
                       u16* f0, u16* tv, long ps)
{
    int n = blockIdx.x, u = threadIdx.x;
    size_t o = (size_t)n * 256 + u;
    float s1 = bf2f(xl[o]);
    float a1x = bf2f(xl[ps + o]), a1y = bf2f(xl[2 * ps + o]), a1z = bf2f(xl[3 * ps + o]);
    float s2 = bf2f(xr_[o]);
    float b1x = bf2f(xr_[ps + o]), b1y = bf2f(xr_[2 * ps + o]), b1z = bf2f(xr_[3 * ps + o]);
    float xs = bf2f(f0[(size_t)n * 512 + u]);
    float rx = bf2f(xv[o]), ry = bf2f(xv[ps + o]), rz = bf2f(xv[2 * ps + o]);
    float w0 = tpw[u], w1 = tpw[256 + u], w2 = tpw[512 + u], w3 = tpw[768 + u], w4 = tpw[1024 + u];

    float dot = a1x * b1x + a1y * b1y + a1z * b1z;
    float cx = a1y * b1z - a1z * b1y;
    float cy = a1z * b1x - a1x * b1z;
    float cz = a1x * b1y - a1y * b1x;

    float out0 = A0C * (w0 * s1 * s2 + w3 * INV3C * dot) + xs;
    float ox = A1C * (INV3C * (w1 * s1 * b1x + w2 * s2 * a1x) + INV6C * w4 * cx) + rx;
    float oy = A1C * (INV3C * (w1 * s1 * b1y + w2 * s2 * a1y) + INV6C * w4 * cy) + ry;
    float oz = A1C * (INV3C * (w1 * s1 * b1z + w2 * s2 * a1z) + INV6C * w4 * cz) + rz;

    float nv = sqrtf(ox * ox + oy * oy + oz * oz + 1e-12f);
    f0[(size_t)n * 512 + u] = f2bf(out0);
    f0[(size_t)n * 512 + 256 + u] = f2bf(nv);
    tv[o] = f2bf(ox);
    tv[ps + o] = f2bf(oy);
    tv[2 * ps + o] = f2bf(oz);
}

// ---------------- repack planar -> interleaved + old_fii (LDS transpose) ----------------
__global__ void repack(const u16* __restrict__ outp, const float* __restrict__ old,
                       float* __restrict__ out, long ps)
{
    __shared__ float add[1024];
    int n = blockIdx.x, u = threadIdx.x;
    size_t o = (size_t)n * 256 + u;
    add[u] = bf2f(outp[o]);
    float vx = bf2f(outp[ps + o]);
    float vy = bf2f(outp[2 * ps + o]);
    float vz = bf2f(outp[3 * ps + o]);
    add[256 + 3 * u] = vx;
    add[256 + 3 * u + 1] = vy;
    add[256 + 3 * u + 2] = vz;
    __syncthreads();
    float4 o4 = ((const float4*)(old + (size_t)n * 1024))[u];
    float4 r;
    r.x = o4.x + add[4 * u];
    r.y = o4.y + add[4 * u + 1];
    r.z = o4.z + add[4 * u + 2];
    r.w = o4.w + add[4 * u + 3];
    ((float4*)(out + (size_t)n * 1024))[u] = r;
}

// weight offsets (u16 elements)
enum {
    OFF_ng12w1 = 0,        // 1024x512
    OFF_ng1w2  = 524288,   // 2 x 512x512 (stride 262144)
    OFF_ngow1  = 1048576,
    OFF_ngow2  = 1310720,
    OFF_l12w0  = 1572864,  // 2 x 256x256 (stride 65536)
    OFF_l12w1  = 1703936,  // 2 x 256x256
    OFF_l3w0   = 1835008,
    OFF_l3w1   = 1900544
};
#define BIAS_BYTE_OFF 3932160
enum { BOFF_mlp1 = 0, BOFF_mlp2 = 1024, BOFF_ngo1 = 2048, BOFF_ngo2 = 2560,
       BOFF_l12 = 3072, BOFF_l3 = 3584 };

extern "C" void kernel_launch(void* const* d_in, const int* in_sizes, int n_in,
                              void* d_out, int out_size, void* d_ws, size_t ws_size,
                              hipStream_t stream) {
    const float* x      = (const float*)d_in[0];
    const float* oldf   = (const float*)d_in[1];
    const float* ng1_w1 = (const float*)d_in[2];
    const float* ng1_b1 = (const float*)d_in[3];
    const float* ng1_w2 = (const float*)d_in[4];
    const float* ng1_b2 = (const float*)d_in[5];
    const float* ng2_w1 = (const float*)d_in[6];
    const float* ng2_b1 = (const float*)d_in[7];
    const float* ng2_w2 = (const float*)d_in[8];
    const float* ng2_b2 = (const float*)d_in[9];
    const float* ngo_w1 = (const float*)d_in[10];
    const float* ngo_b1 = (const float*)d_in[11];
    const float* ngo_w2 = (const float*)d_in[12];
    const float* ngo_b2 = (const float*)d_in[13];
    const float* l1_w0  = (const float*)d_in[14];
    const float* l1_b0  = (const float*)d_in[15];
    const float* l1_w1  = (const float*)d_in[16];
    const float* l2_w0  = (const float*)d_in[17];
    const float* l2_b0  = (const float*)d_in[18];
    const float* l2_w1  = (const float*)d_in[19];
    const float* l3_w0  = (const float*)d_in[20];
    const float* l3_b0  = (const float*)d_in[21];
    const float* l3_w1  = (const float*)d_in[22];
    const float* tpw    = (const float*)d_in[23];

    u16* wts = (u16*)d_ws;
    char* wsb = (char*)d_ws;
    float* biasf = (float*)(wsb + BIAS_BYTE_OFF);

    WArgs wa;
    wa.w[0]  = { ng1_w1, wts + OFF_ng12w1,          512, 1.0f };
    wa.w[1]  = { ng2_w1, wts + OFF_ng12w1 + 262144, 512, 1.0f };
    wa.w[2]  = { ng1_w2, wts + OFF_ng1w2,           512, 1.0f };
    wa.w[3]  = { ng2_w2, wts + OFF_ng1w2 + 262144,  512, 1.0f };
    wa.w[4]  = { ngo_w1, wts + OFF_ngow1,           512, 1.0f };
    wa.w[5]  = { ngo_w2, wts + OFF_ngow2,           512, 1.0f };
    wa.w[6]  = { l1_w0, wts + OFF_l12w0,            256, 0.0625f };
    wa.w[7]  = { l2_w0, wts + OFF_l12w0 + 65536,    256, 0.0625f };
    wa.w[8]  = { l1_w1, wts + OFF_l12w1,            256, 0.0625f };
    wa.w[9]  = { l2_w1, wts + OFF_l12w1 + 65536,    256, 0.0625f };
    wa.w[10] = { l3_w0, wts + OFF_l3w0,             256, 0.0625f };
    wa.w[11] = { l3_w1, wts + OFF_l3w1,             256, 0.0625f };
    cvt_weights<<<dim3(16, 16, 12), dim3(32, 8), 0, stream>>>(wa);

    BArgs ba;
    ba.b[0] = { ng1_b1, biasf + BOFF_mlp1,       512 };
    ba.b[1] = { ng2_b1, biasf + BOFF_mlp1 + 512, 512 };
    ba.b[2] = { ng1_b2, biasf + BOFF_mlp2,       512 };
    ba.b[3] = { ng2_b2, biasf + BOFF_mlp2 + 512, 512 };
    ba.b[4] = { ngo_b1, biasf + BOFF_ngo1,       512 };
    ba.b[5] = { ngo_b2, biasf + BOFF_ngo2,       512 };
    ba.b[6] = { l1_b0, biasf + BOFF_l12,         256 };
    ba.b[7] = { l2_b0, biasf + BOFF_l12 + 256,   256 };
    ba.b[8] = { l3_b0, biasf + BOFF_l3,          256 };
    pack_bias<<<9, 256, 0, stream>>>(ba);

    long Nn = (long)in_sizes[0] / 1024;

    // chunking: ws fit only (peak = 4MiB + Nc*10752 bytes)
    int c = 1;
    while (c < 256 &&
           (unsigned long long)(4ULL << 20) + (unsigned long long)(Nn / c) * 10752ULL > (unsigned long long)ws_size)
        c <<= 1;
    long Nc = Nn / c;

    u16* F0 = (u16*)(wsb + (4 << 20));       // [Nc,512]
    u16* H  = F0 + (size_t)Nc * 512;         // [Nc,1024]
    u16* G  = H + (size_t)Nc * 1024;         // [Nc,1024]
    u16* XV = G + (size_t)Nc * 1024;         // [3][Nc,256]
    u16* XL = XV + (size_t)Nc * 768;         // [2 sides][4 planes][Nc,256]
    long ps = Nc * 256;
    u16* XR = XL + 4 * ps;
    u16* TV = XR + ps;                       // aliases XR vector planes
    u16* OUTP = XL;                          // aliases XL (dead after tp_res)

    dim3 blk(512);
    const size_t SMEM = 131072;
    int mt = (int)(Nc / 256);

    for (int ch = 0; ch < c; ++ch) {
        const float* xk  = x + (size_t)ch * Nc * 1024;
        const float* ok  = oldf + (size_t)ch * Nc * 1024;
        float* outk = (float*)d_out + (size_t)ch * Nc * 1024;

        prep_f0<<<(int)Nc, 256, 0, stream>>>(xk, F0, XV, ps);

        // MLP1 fused (ng1|ng2): H[Nc,1024] = silu(F0 @ W^T + b)
        gemm256<<<dim3(mt * 4, 1), blk, SMEM, stream>>>(F0, 512, 0, nullptr, nullptr, 0, 0,
            wts + OFF_ng12w1, 0, 0, biasf + BOFF_mlp1, 0, H, 1024, 0, 0, 512, Nc, 0, 1, 2);
        // MLP2 z-batched: G[:, z*512:] = H[:, z*512:] @ w2_z^T + b
        gemm256<<<dim3(mt * 2, 2), blk, SMEM, stream>>>(H, 1024, 512, nullptr, nullptr, 0, 0,
            wts + OFF_ng1w2, 262144, 0, biasf + BOFF_mlp2, 512, G, 1024, 512, 0, 512, Nc, 0, 0, 1);
        // merged irrep-linears lin1/lin2: z=2 sides, M=4*Nc (plane 0 scalar, 1-3 gated XV)
        gemm256<<<dim3(mt * 4, 2), blk, SMEM, stream>>>(G, 1024, 512, XV, G, 1024, 512,
            wts + OFF_l12w0, 65536, 131072, biasf + BOFF_l12, 256, XL, 256, 4 * ps, ps, 256, Nc, 2, 0, 0);

        // tensor product + residual -> F0', TV
        tp_res<<<(int)Nc, 256, 0, stream>>>(XL, XR, tpw, XV, F0, TV, ps);

        // ngo MLP (N=512)
        gemm256<<<dim3(mt * 2, 1), blk, SMEM, stream>>>(F0, 512, 0, nullptr, nullptr, 0, 0,
            wts + OFF_ngow1, 0, 0, biasf + BOFF_ngo1, 0, H, 512, 0, 0, 512, Nc, 0, 1, 1);
        gemm256<<<dim3(mt * 2, 1), blk, SMEM, stream>>>(H, 512, 0, nullptr, nullptr, 0, 0,
            wts + OFF_ngow2, 0, 0, biasf + BOFF_ngo2, 0, G, 512, 0, 0, 512, Nc, 0, 0, 1);
        // merged lin3: z=1, M=4*Nc (plane 0 scalar from G, 1-3 gated TV)
        gemm256<<<dim3(mt * 4, 1), blk, SMEM, stream>>>(G, 512, 0, TV, G, 512, 0,
            wts + OFF_l3w0, 0, 65536, biasf + BOFF_l3, 0, OUTP, 256, 0, ps, 256, Nc, 2, 0, 0);

        // repack + old_fii -> out
        repack<<<(int)Nc, 256, 0, stream>>>(OUTP, ok, outk, ps);
    }
}

// Round 6
// 504.292 us; speedup vs baseline: 1.5716x; 1.0692x over previous
//
#include <hip/hip_runtime.h>
#include <stdint.h>
#include <math.h>

typedef unsigned short u16;
typedef __attribute__((ext_vector_type(8))) short short8;
typedef __attribute__((ext_vector_type(4))) float f32x4;

#define A0C 0.44721359549995793f
#define A1C 0.77459666924148340f
#define INV3C 0.57735026918962584f
#define INV6C 0.40824829046386302f

__device__ __forceinline__ float bf2f(u16 u) {
    unsigned v = ((unsigned)u) << 16; float f; __builtin_memcpy(&f, &v, 4); return f;
}
__device__ __forceinline__ u16 f2bf(float f) {
    unsigned u; __builtin_memcpy(&u, &f, 4);
    u += 0x7fffu + ((u >> 16) & 1u);
    return (u16)(u >> 16);
}

__device__ __forceinline__ void gload_lds16(const void* g, void* l) {
    __builtin_amdgcn_global_load_lds((const __attribute__((address_space(1))) unsigned*)g,
                                     (__attribute__((address_space(3))) unsigned*)l, 16, 0, 0);
}

union S8 { short8 v; u16 h[8]; };

// ---------------- weight transpose + bf16 convert ----------------
struct WDesc { const float* s; u16* d; int n; float sc; };
struct WArgs { WDesc w[12]; };

__global__ void cvt_weights(WArgs args) {
    WDesc wd = args.w[blockIdx.z];
    int n = wd.n;
    int x0 = blockIdx.x * 32, y0 = blockIdx.y * 32;
    if (x0 >= n || y0 >= n) return;
    __shared__ float tile[32][33];
    int tx = threadIdx.x, ty = threadIdx.y;
#pragma unroll
    for (int j = 0; j < 4; j++)
        tile[ty + 8 * j][tx] = wd.s[(size_t)(y0 + ty + 8 * j) * n + x0 + tx];
    __syncthreads();
#pragma unroll
    for (int j = 0; j < 4; j++)
        wd.d[(size_t)(x0 + ty + 8 * j) * n + y0 + tx] = f2bf(tile[tx][ty + 8 * j] * wd.sc);
}

// ---------------- bias pack ----------------
struct BDesc { const float* s; float* d; int n; };
struct BArgs { BDesc b[9]; };
__global__ void pack_bias(BArgs a) {
    BDesc b = a.b[blockIdx.x];
    for (int i = threadIdx.x; i < b.n; i += 256) b.d[i] = b.s[i];
}

// ---------------- prep: f0 = [s,|v|] bf16, XV planar bf16 (8 elems/thread) ----------------
__global__ void prep_f0(const float* __restrict__ x, u16* __restrict__ f0,
                        u16* __restrict__ xv, long ps) {
    int t = blockIdx.x * 256 + threadIdx.x;
    long n = t >> 5;
    int u0 = (t & 31) * 8;
    const float* xr = x + (size_t)n * 1024;
    float4 s0 = *(const float4*)(xr + u0);
    float4 s1 = *(const float4*)(xr + u0 + 4);
    float vv[24];
#pragma unroll
    for (int i = 0; i < 6; i++) {
        float4 w = *(const float4*)(xr + 256 + 3 * u0 + 4 * i);
        vv[4 * i] = w.x; vv[4 * i + 1] = w.y; vv[4 * i + 2] = w.z; vv[4 * i + 3] = w.w;
    }
    float sc[8] = { s0.x, s0.y, s0.z, s0.w, s1.x, s1.y, s1.z, s1.w };
    S8 fs, fn, px, py, pz;
#pragma unroll
    for (int j = 0; j < 8; j++) {
        float a = vv[3 * j], b = vv[3 * j + 1], c = vv[3 * j + 2];
        float nv = sqrtf(a * a + b * b + c * c + 1e-12f);
        fs.h[j] = f2bf(sc[j]);
        fn.h[j] = f2bf(nv);
        px.h[j] = f2bf(a); py.h[j] = f2bf(b); pz.h[j] = f2bf(c);
    }
    size_t o = (size_t)n * 256 + u0;
    *(short8*)(f0 + (size_t)n * 512 + u0) = fs.v;
    *(short8*)(f0 + (size_t)n * 512 + 256 + u0) = fn.v;
    *(short8*)(xv + o) = px.v;
    *(short8*)(xv + ps + o) = py.v;
    *(short8*)(xv + 2 * ps + o) = pz.v;
}

// ---------------- GEMM 256x256 tile, BK=64, dbuf LDS, T2 swizzle ----------------
// mode 0: A = Ap + zi*az + row*lda (bf16), C = C + zi*czs + row*ldc
// mode 2 (merged irrep-linear): rows plane-stacked, M = 4*nc; plane p = row/nc:
//   p==0: A = Ap + zi*az + rr*lda (scalar block), B = Bt + zi*bz, bias on
//   p>=1: A[rr][u] = xsrc[(row-nc)*256+u] * gp[zi*gz + rr*gld + 256+u], B += bw, no bias
//   C = C + zi*czs + p*czp + rr*ldc
// MFMA operands SWAPPED (mfma(b,a)): lane&15 -> M-row, hk*4+reg -> N-col
//   => each lane packs 4 consecutive cols into one 8B store.
__global__ __launch_bounds__(512, 2)
void gemm256(const u16* __restrict__ Ap, int lda, long az,
             const u16* __restrict__ xsrc,
             const u16* __restrict__ gp, int gld, long gz,
             const u16* __restrict__ Bt, long bz, long bw,
             const float* __restrict__ bias, int bsz,
             u16* __restrict__ C, int ldc, long czs, long czp,
             int K, long nc, int mode, int act, int nshift)
{
    extern __shared__ __align__(16) u16 sm[];   // 2 x (A 256*64 + B 256*64) = 128 KiB
    u16* As = sm;
    u16* Bs = sm + 32768;

    const int tid = threadIdx.x;
    const int lane = tid & 63;
    const int wid = tid >> 6;
    const int wr = wid >> 2, wc = wid & 3;
    const int lr = lane & 15, hk = lane >> 4;

    // bijective XCD-chunked swizzle
    int nwg = gridDim.x;
    int lid = blockIdx.x;
    int wg;
    if ((nwg & 7) == 0) { int q = nwg >> 3; wg = (lid & 7) * q + (lid >> 3); }
    else wg = lid;
    const long row0 = (long)(wg >> nshift) * 256;
    const int n0 = (wg & ((1 << nshift) - 1)) * 256;
    const int zi = blockIdx.y;

    long p = 0, rr0 = row0;
    if (mode == 2) { p = row0 / nc; rr0 = row0 - p * nc; }

    const u16* Bz = Bt + (size_t)zi * bz + ((mode == 2 && p > 0) ? bw : 0);
    const long cbase = (mode == 2) ? (zi * czs + p * czp + rr0 * ldc)
                                   : (zi * czs + row0 * ldc);

    f32x4 acc[8][4];
#pragma unroll
    for (int m = 0; m < 8; m++)
#pragma unroll
        for (int n = 0; n < 4; n++) acc[m][n] = (f32x4){0.f, 0.f, 0.f, 0.f};

    auto stageB = [&](int buf, int kt) {
#pragma unroll
        for (int it = 0; it < 4; ++it) {
            int idx = it * 512 + tid;
            int r = idx >> 3, s = idx & 7;
            const u16* g = Bz + (size_t)(n0 + r) * K + kt + ((s ^ (r & 7)) * 8);
            u16* l = Bs + buf * 16384 + (size_t)(it * 512 + (tid & 0x1C0)) * 8;
            gload_lds16(g, l);
        }
    };
    auto stageA0 = [&](int buf, int kt) {
#pragma unroll
        for (int it = 0; it < 4; ++it) {
            int idx = it * 512 + tid;
            int r = idx >> 3, s = idx & 7;
            const u16* g = Ap + (size_t)zi * az + (rr0 + r) * (size_t)lda + kt + ((s ^ (r & 7)) * 8);
            u16* l = As + buf * 16384 + (size_t)(it * 512 + (tid & 0x1C0)) * 8;
            gload_lds16(g, l);
        }
    };
    auto stageA2 = [&](int buf, int kt) {
#pragma unroll
        for (int it = 0; it < 4; ++it) {
            int idx = it * 512 + tid;
            int r = idx >> 3, s = idx & 7;
            int u = kt + s * 8;
            S8 gg, tu, pk;
            gg.v = *(const short8*)(gp + (size_t)zi * gz + (rr0 + r) * (size_t)gld + 256 + u);
            tu.v = *(const short8*)(xsrc + (size_t)(row0 - nc + r) * 256 + u);
#pragma unroll
            for (int j = 0; j < 8; j++) pk.h[j] = f2bf(bf2f(tu.h[j]) * bf2f(gg.h[j]));
            *(short8*)&As[buf * 16384 + ((size_t)r * 8 + (s ^ (r & 7))) * 8] = pk.v;
        }
    };

    const bool a_direct = (mode == 0) || (p == 0);
    const int nt = K >> 6;
    stageB(0, 0);
    if (a_direct) stageA0(0, 0); else stageA2(0, 0);
    __syncthreads();

    int buf = 0;
    for (int t = 0; t < nt; ++t) {
        if (t + 1 < nt) {
            int kt = (t + 1) << 6;
            stageB(buf ^ 1, kt);
            if (a_direct) stageA0(buf ^ 1, kt); else stageA2(buf ^ 1, kt);
        }
        const int ao = buf * 16384, bo = buf * 16384;
#pragma unroll
        for (int kk = 0; kk < 2; ++kk) {
            short8 b[4];
#pragma unroll
            for (int n = 0; n < 4; n++) {
                int cb = wc * 64 + n * 16 + lr;
                int sl = (kk * 4 + hk) ^ (cb & 7);
                b[n] = *(const short8*)&Bs[bo + (size_t)cb * 64 + sl * 8];
            }
#pragma unroll
            for (int m = 0; m < 8; m++) {
                int ra = wr * 128 + m * 16 + lr;
                int sl = (kk * 4 + hk) ^ (ra & 7);
                short8 a = *(const short8*)&As[ao + (size_t)ra * 64 + sl * 8];
#pragma unroll
                for (int n = 0; n < 4; n++)
                    acc[m][n] = __builtin_amdgcn_mfma_f32_16x16x32_bf16(b[n], a, acc[m][n], 0, 0, 0);
            }
        }
        __syncthreads();
        buf ^= 1;
    }

    // ---- epilogue: lane holds 4 consecutive cols -> packed 8B stores ----
    const bool use_bias = bias && (mode == 0 || p == 0);
#pragma unroll
    for (int m = 0; m < 8; m++) {
        long rit = wr * 128 + m * 16 + lr;
        u16* crow = C + cbase + rit * (size_t)ldc;
#pragma unroll
        for (int n = 0; n < 4; n++) {
            int col = n0 + wc * 64 + n * 16 + hk * 4;
            float4 bb = use_bias ? *(const float4*)&bias[(size_t)zi * bsz + col]
                                 : (float4){0.f, 0.f, 0.f, 0.f};
            float v0 = acc[m][n][0] + bb.x;
            float v1 = acc[m][n][1] + bb.y;
            float v2 = acc[m][n][2] + bb.z;
            float v3 = acc[m][n][3] + bb.w;
            if (act) {
                v0 = v0 * (1.0f / (1.0f + __expf(-v0)));
                v1 = v1 * (1.0f / (1.0f + __expf(-v1)));
                v2 = v2 * (1.0f / (1.0f + __expf(-v2)));
                v3 = v3 * (1.0f / (1.0f + __expf(-v3)));
            }
            uint2 st;
            st.x = (unsigned)f2bf(v0) | ((unsigned)f2bf(v1) << 16);
            st.y = (unsigned)f2bf(v2) | ((unsigned)f2bf(v3) << 16);
            *(uint2*)(crow + col) = st;
        }
    }
}

// ---------------- tensor product + residual -> f0', tv planes (8 elems/thread) ----------------
// tv aliases xr_+ps; f0 read then overwritten. Same-thread read-before-write only.
__global__ void tp_res(const u16* __restrict__ xl, const u16* xr_,
                       const float* __restrict__ tpw, const u16* __restrict__ xv,
                       u16* f0, u16* tv, long ps)
{
    int t = blockIdx.x * 256 + threadIdx.x;
    long n = t >> 5;
    int u0 = (t & 31) * 8;
    size_t o = (size_t)n * 256 + u0;

    S8 S1, AX, AY, AZ, S2, BX, BY, BZ, XS, RX, RY, RZ;
    S1.v = *(const short8*)(xl + o);
    AX.v = *(const short8*)(xl + ps + o);
    AY.v = *(const short8*)(xl + 2 * ps + o);
    AZ.v = *(const short8*)(xl + 3 * ps + o);
    S2.v = *(const short8*)(xr_ + o);
    BX.v = *(const short8*)(xr_ + ps + o);
    BY.v = *(const short8*)(xr_ + 2 * ps + o);
    BZ.v = *(const short8*)(xr_ + 3 * ps + o);
    XS.v = *(const short8*)(f0 + (size_t)n * 512 + u0);
    RX.v = *(const short8*)(xv + o);
    RY.v = *(const short8*)(xv + ps + o);
    RZ.v = *(const short8*)(xv + 2 * ps + o);

    float W[5][8];
#pragma unroll
    for (int q = 0; q < 5; q++) {
        float4 a = *(const float4*)(tpw + q * 256 + u0);
        float4 b = *(const float4*)(tpw + q * 256 + u0 + 4);
        W[q][0] = a.x; W[q][1] = a.y; W[q][2] = a.z; W[q][3] = a.w;
        W[q][4] = b.x; W[q][5] = b.y; W[q][6] = b.z; W[q][7] = b.w;
    }

    S8 O0, NV, TX, TY, TZ;
#pragma unroll
    for (int j = 0; j < 8; j++) {
        float s1 = bf2f(S1.h[j]), a1x = bf2f(AX.h[j]), a1y = bf2f(AY.h[j]), a1z = bf2f(AZ.h[j]);
        float s2 = bf2f(S2.h[j]), b1x = bf2f(BX.h[j]), b1y = bf2f(BY.h[j]), b1z = bf2f(BZ.h[j]);
        float dot = a1x * b1x + a1y * b1y + a1z * b1z;
        float cx = a1y * b1z - a1z * b1y;
        float cy = a1z * b1x - a1x * b1z;
        float cz = a1x * b1y - a1y * b1x;
        float out0 = A0C * (W[0][j] * s1 * s2 + W[3][j] * INV3C * dot) + bf2f(XS.h[j]);
        float ox = A1C * (INV3C * (W[1][j] * s1 * b1x + W[2][j] * s2 * a1x) + INV6C * W[4][j] * cx) + bf2f(RX.h[j]);
        float oy = A1C * (INV3C * (W[1][j] * s1 * b1y + W[2][j] * s2 * a1y) + INV6C * W[4][j] * cy) + bf2f(RY.h[j]);
        float oz = A1C * (INV3C * (W[1][j] * s1 * b1z + W[2][j] * s2 * a1z) + INV6C * W[4][j] * cz) + bf2f(RZ.h[j]);
        float nv = sqrtf(ox * ox + oy * oy + oz * oz + 1e-12f);
        O0.h[j] = f2bf(out0);
        NV.h[j] = f2bf(nv);
        TX.h[j] = f2bf(ox); TY.h[j] = f2bf(oy); TZ.h[j] = f2bf(oz);
    }
    *(short8*)(f0 + (size_t)n * 512 + u0) = O0.v;
    *(short8*)(f0 + (size_t)n * 512 + 256 + u0) = NV.v;
    *(short8*)(tv + o) = TX.v;
    *(short8*)(tv + ps + o) = TY.v;
    *(short8*)(tv + 2 * ps + o) = TZ.v;
}

// ---------------- repack planar -> interleaved + old_fii (8 elems/thread) ----------------
__global__ void repack(const u16* __restrict__ outp, const float* __restrict__ old,
                       float* __restrict__ out, long ps)
{
    int t = blockIdx.x * 256 + threadIdx.x;
    long n = t >> 5;
    int u0 = (t & 31) * 8;
    size_t o = (size_t)n * 256 + u0;

    S8 S, VX, VY, VZ;
    S.v  = *(const short8*)(outp + o);
    VX.v = *(const short8*)(outp + ps + o);
    VY.v = *(const short8*)(outp + 2 * ps + o);
    VZ.v = *(const short8*)(outp + 3 * ps + o);

    const float* oldr = old + (size_t)n * 1024;
    float* outr = out + (size_t)n * 1024;

    // scalar part: 8 floats at u0
#pragma unroll
    for (int i = 0; i < 2; i++) {
        float4 ov = *(const float4*)(oldr + u0 + 4 * i);
        float4 r;
        r.x = ov.x + bf2f(S.h[4 * i]);
        r.y = ov.y + bf2f(S.h[4 * i + 1]);
        r.z = ov.z + bf2f(S.h[4 * i + 2]);
        r.w = ov.w + bf2f(S.h[4 * i + 3]);
        *(float4*)(outr + u0 + 4 * i) = r;
    }
    // vector part: 24 interleaved floats at 256 + 3*u0
    float vv[24];
#pragma unroll
    for (int j = 0; j < 8; j++) {
        vv[3 * j] = bf2f(VX.h[j]);
        vv[3 * j + 1] = bf2f(VY.h[j]);
        vv[3 * j + 2] = bf2f(VZ.h[j]);
    }
#pragma unroll
    for (int i = 0; i < 6; i++) {
        float4 ov = *(const float4*)(oldr + 256 + 3 * u0 + 4 * i);
        float4 r;
        r.x = ov.x + vv[4 * i];
        r.y = ov.y + vv[4 * i + 1];
        r.z = ov.z + vv[4 * i + 2];
        r.w = ov.w + vv[4 * i + 3];
        *(float4*)(outr + 256 + 3 * u0 + 4 * i) = r;
    }
}

// weight offsets (u16 elements)
enum {
    OFF_ng12w1 = 0,        // 1024x512
    OFF_ng1w2  = 524288,   // 2 x 512x512 (stride 262144)
    OFF_ngow1  = 1048576,
    OFF_ngow2  = 1310720,
    OFF_l12w0  = 1572864,  // 2 x 256x256 (stride 65536)
    OFF_l12w1  = 1703936,  // 2 x 256x256
    OFF_l3w0   = 1835008,
    OFF_l3w1   = 1900544
};
#define BIAS_BYTE_OFF 3932160
enum { BOFF_mlp1 = 0, BOFF_mlp2 = 1024, BOFF_ngo1 = 2048, BOFF_ngo2 = 2560,
       BOFF_l12 = 3072, BOFF_l3 = 3584 };

extern "C" void kernel_launch(void* const* d_in, const int* in_sizes, int n_in,
                              void* d_out, int out_size, void* d_ws, size_t ws_size,
                              hipStream_t stream) {
    const float* x      = (const float*)d_in[0];
    const float* oldf   = (const float*)d_in[1];
    const float* ng1_w1 = (const float*)d_in[2];
    const float* ng1_b1 = (const float*)d_in[3];
    const float* ng1_w2 = (const float*)d_in[4];
    const float* ng1_b2 = (const float*)d_in[5];
    const float* ng2_w1 = (const float*)d_in[6];
    const float* ng2_b1 = (const float*)d_in[7];
    const float* ng2_w2 = (const float*)d_in[8];
    const float* ng2_b2 = (const float*)d_in[9];
    const float* ngo_w1 = (const float*)d_in[10];
    const float* ngo_b1 = (const float*)d_in[11];
    const float* ngo_w2 = (const float*)d_in[12];
    const float* ngo_b2 = (const float*)d_in[13];
    const float* l1_w0  = (const float*)d_in[14];
    const float* l1_b0  = (const float*)d_in[15];
    const float* l1_w1  = (const float*)d_in[16];
    const float* l2_w0  = (const float*)d_in[17];
    const float* l2_b0  = (const float*)d_in[18];
    const float* l2_w1  = (const float*)d_in[19];
    const float* l3_w0  = (const float*)d_in[20];
    const float* l3_b0  = (const float*)d_in[21];
    const float* l3_w1  = (const float*)d_in[22];
    const float* tpw    = (const float*)d_in[23];

    u16* wts = (u16*)d_ws;
    char* wsb = (char*)d_ws;
    float* biasf = (float*)(wsb + BIAS_BYTE_OFF);

    WArgs wa;
    wa.w[0]  = { ng1_w1, wts + OFF_ng12w1,          512, 1.0f };
    wa.w[1]  = { ng2_w1, wts + OFF_ng12w1 + 262144, 512, 1.0f };
    wa.w[2]  = { ng1_w2, wts + OFF_ng1w2,           512, 1.0f };
    wa.w[3]  = { ng2_w2, wts + OFF_ng1w2 + 262144,  512, 1.0f };
    wa.w[4]  = { ngo_w1, wts + OFF_ngow1,           512, 1.0f };
    wa.w[5]  = { ngo_w2, wts + OFF_ngow2,           512, 1.0f };
    wa.w[6]  = { l1_w0, wts + OFF_l12w0,            256, 0.0625f };
    wa.w[7]  = { l2_w0, wts + OFF_l12w0 + 65536,    256, 0.0625f };
    wa.w[8]  = { l1_w1, wts + OFF_l12w1,            256, 0.0625f };
    wa.w[9]  = { l2_w1, wts + OFF_l12w1 + 65536,    256, 0.0625f };
    wa.w[10] = { l3_w0, wts + OFF_l3w0,             256, 0.0625f };
    wa.w[11] = { l3_w1, wts + OFF_l3w1,             256, 0.0625f };
    cvt_weights<<<dim3(16, 16, 12), dim3(32, 8), 0, stream>>>(wa);

    BArgs ba;
    ba.b[0] = { ng1_b1, biasf + BOFF_mlp1,       512 };
    ba.b[1] = { ng2_b1, biasf + BOFF_mlp1 + 512, 512 };
    ba.b[2] = { ng1_b2, biasf + BOFF_mlp2,       512 };
    ba.b[3] = { ng2_b2, biasf + BOFF_mlp2 + 512, 512 };
    ba.b[4] = { ngo_b1, biasf + BOFF_ngo1,       512 };
    ba.b[5] = { ngo_b2, biasf + BOFF_ngo2,       512 };
    ba.b[6] = { l1_b0, biasf + BOFF_l12,         256 };
    ba.b[7] = { l2_b0, biasf + BOFF_l12 + 256,   256 };
    ba.b[8] = { l3_b0, biasf + BOFF_l3,          256 };
    pack_bias<<<9, 256, 0, stream>>>(ba);

    long Nn = (long)in_sizes[0] / 1024;

    // chunking: ws fit only (peak = 4MiB + Nc*10752 bytes)
    int c = 1;
    while (c < 256 &&
           (unsigned long long)(4ULL << 20) + (unsigned long long)(Nn / c) * 10752ULL > (unsigned long long)ws_size)
        c <<= 1;
    long Nc = Nn / c;

    u16* F0 = (u16*)(wsb + (4 << 20));       // [Nc,512]
    u16* H  = F0 + (size_t)Nc * 512;         // [Nc,1024]
    u16* G  = H + (size_t)Nc * 1024;         // [Nc,1024]
    u16* XV = G + (size_t)Nc * 1024;         // [3][Nc,256]
    u16* XL = XV + (size_t)Nc * 768;         // [2 sides][4 planes][Nc,256]
    long ps = Nc * 256;
    u16* XR = XL + 4 * ps;
    u16* TV = XR + ps;                       // aliases XR vector planes
    u16* OUTP = XL;                          // aliases XL (dead after tp_res)

    dim3 blk(512);
    const size_t SMEM = 131072;
    int mt = (int)(Nc / 256);
    int eb = (int)(Nc / 8);

    for (int ch = 0; ch < c; ++ch) {
        const float* xk  = x + (size_t)ch * Nc * 1024;
        const float* ok  = oldf + (size_t)ch * Nc * 1024;
        float* outk = (float*)d_out + (size_t)ch * Nc * 1024;

        prep_f0<<<eb, 256, 0, stream>>>(xk, F0, XV, ps);

        // MLP1 fused (ng1|ng2): H[Nc,1024] = silu(F0 @ W^T + b)
        gemm256<<<dim3(mt * 4, 1), blk, SMEM, stream>>>(F0, 512, 0, nullptr, nullptr, 0, 0,
            wts + OFF_ng12w1, 0, 0, biasf + BOFF_mlp1, 0, H, 1024, 0, 0, 512, Nc, 0, 1, 2);
        // MLP2 z-batched: G[:, z*512:] = H[:, z*512:] @ w2_z^T + b
        gemm256<<<dim3(mt * 2, 2), blk, SMEM, stream>>>(H, 1024, 512, nullptr, nullptr, 0, 0,
            wts + OFF_ng1w2, 262144, 0, biasf + BOFF_mlp2, 512, G, 1024, 512, 0, 512, Nc, 0, 0, 1);
        // merged irrep-linears lin1/lin2: z=2 sides, M=4*Nc (plane 0 scalar, 1-3 gated XV)
        gemm256<<<dim3(mt * 4, 2), blk, SMEM, stream>>>(G, 1024, 512, XV, G, 1024, 512,
            wts + OFF_l12w0, 65536, 131072, biasf + BOFF_l12, 256, XL, 256, 4 * ps, ps, 256, Nc, 2, 0, 0);

        // tensor product + residual -> F0', TV
        tp_res<<<eb, 256, 0, stream>>>(XL, XR, tpw, XV, F0, TV, ps);

        // ngo MLP (N=512)
        gemm256<<<dim3(mt * 2, 1), blk, SMEM, stream>>>(F0, 512, 0, nullptr, nullptr, 0, 0,
            wts + OFF_ngow1, 0, 0, biasf + BOFF_ngo1, 0, H, 512, 0, 0, 512, Nc, 0, 1, 1);
        gemm256<<<dim3(mt * 2, 1), blk, SMEM, stream>>>(H, 512, 0, nullptr, nullptr, 0, 0,
            wts + OFF_ngow2, 0, 0, biasf + BOFF_ngo2, 0, G, 512, 0, 0, 512, Nc, 0, 0, 1);
        // merged lin3: z=1, M=4*Nc (plane 0 scalar from G, 1-3 gated TV)
        gemm256<<<dim3(mt * 4, 1), blk, SMEM, stream>>>(G, 512, 0, TV, G, 512, 0,
            wts + OFF_l3w0, 0, 65536, biasf + BOFF_l3, 0, OUTP, 256, 0, ps, 256, Nc, 2, 0, 0);

        // repack + old_fii -> out
        repack<<<eb, 256, 0, stream>>>(OUTP, ok, outk, ps);
    }
}